// Round 1
// baseline (714.583 us; speedup 1.0000x reference)
//
#include <hip/hip_runtime.h>
#include <hip/hip_bf16.h>

#define HW 65536
#define WST 29952   // per-sample effective-weight stride (floats)

__device__ inline unsigned short f2bf(float f) {
  union { float f; unsigned u; } v; v.f = f;
  unsigned r = v.u + 0x7FFF + ((v.u >> 16) & 1);   // RNE
  return (unsigned short)(r >> 16);
}
__device__ inline float bf2f(unsigned short h) {
  union { unsigned u; float f; } v; v.u = ((unsigned)h) << 16;
  return v.f;
}

// ---------------- kernel 1: per-sample effective weights (top-1 gate folded) ----
__global__ void k_weights(const float* __restrict__ probs,
    const float* __restrict__ w1, const float* __restrict__ la1, const float* __restrict__ lb1,
    const float* __restrict__ w2, const float* __restrict__ la2, const float* __restrict__ lb2,
    const float* __restrict__ wsca, const float* __restrict__ lasca, const float* __restrict__ lbsca,
    const float* __restrict__ w3, const float* __restrict__ la3, const float* __restrict__ lb3,
    const float* __restrict__ w4, const float* __restrict__ la4, const float* __restrict__ lb4,
    const float* __restrict__ w5, const float* __restrict__ la5, const float* __restrict__ lb5,
    const float* __restrict__ b3, const float* __restrict__ b5,
    const float* __restrict__ beta, const float* __restrict__ gamma,
    float* __restrict__ weff)
{
  int b = blockIdx.x, tid = threadIdx.x;
  float p0 = probs[b*3+0], p1 = probs[b*3+1], p2 = probs[b*3+2];
  int e = 0; float g = p0;
  if (p1 > g) { g = p1; e = 1; }
  if (p2 > g) { g = p2; e = 2; }
  float s = 2.0f * g;               // SCALING * gate
  float* wb = weff + b * WST;
  for (int idx = tid; idx < 8192; idx += 256) {     // w1e [j][c]  @0
    int j = idx >> 6, c = idx & 63;
    float acc = w1[idx];
    #pragma unroll
    for (int r = 0; r < 4; ++r)
      acc += s * lb1[(e*128 + j)*4 + r] * la1[(e*4 + r)*64 + c];
    wb[idx] = acc;
  }
  for (int idx = tid; idx < 1152; idx += 256) {     // w2e [j][3x3] @8192
    int row = idx / 3, dx = idx - row*3;            // row = j*3+dy
    float acc = w2[idx];
    #pragma unroll
    for (int r = 0; r < 12; ++r)
      acc += s * lb2[e*4608 + row*12 + r] * la2[e*36 + r*3 + dx];
    wb[8192 + idx] = acc;
  }
  for (int idx = tid; idx < 4096; idx += 256) {     // wscat [c][k] @9344
    int c = idx >> 6, k = idx & 63;
    float acc = wsca[k*64 + c];
    #pragma unroll
    for (int r = 0; r < 4; ++r)
      acc += s * lbsca[(e*64 + k)*4 + r] * lasca[(e*4 + r)*64 + c];
    wb[9344 + idx] = acc;
  }
  for (int idx = tid; idx < 4096; idx += 256) {     // w3bt [k][c] (T, beta-folded) @13440
    int k = idx >> 6, c = idx & 63;
    float acc = w3[c*64 + k];
    #pragma unroll
    for (int r = 0; r < 4; ++r)
      acc += s * lb3[(e*64 + c)*4 + r] * la3[(e*4 + r)*64 + k];
    wb[13440 + idx] = acc * beta[c];
  }
  for (int idx = tid; idx < 8192; idx += 256) {     // w4t [cp][j] (T) @17536
    int cp = idx >> 7, j = idx & 127;
    float acc = w4[j*64 + cp];
    #pragma unroll
    for (int r = 0; r < 4; ++r)
      acc += s * lb4[(e*128 + j)*4 + r] * la4[(e*4 + r)*64 + cp];
    wb[17536 + idx] = acc;
  }
  for (int idx = tid; idx < 4096; idx += 256) {     // w5gt [k][c] (T, gamma-folded) @25728
    int k = idx >> 6, c = idx & 63;
    float acc = w5[c*64 + k];
    #pragma unroll
    for (int r = 0; r < 4; ++r)
      acc += s * lb5[(e*64 + c)*4 + r] * la5[(e*4 + r)*64 + k];
    wb[25728 + idx] = acc * gamma[c];
  }
  if (tid < 64) {
    wb[29824 + tid] = b3[tid] * beta[tid];   // beta-folded b3
    wb[29888 + tid] = b5[tid] * gamma[tid];  // gamma-folded b5
  }
}

// ---------------- kernel 2: LN1 + conv1(1x1,64->128) + dw3x3 + SimpleGate + pool ----
// tile 4x32 pixels, halo 6x34=204. thread<204 owns one halo pixel (all 128 outputs,
// weight indices wave-uniform -> scalar loads).
__global__ __launch_bounds__(256, 2) void k_stage1(
    const float* __restrict__ inp, const float* __restrict__ ln1w, const float* __restrict__ ln1b,
    const float* __restrict__ b1, const float* __restrict__ b2,
    const float* __restrict__ weff, unsigned short* __restrict__ z, float* __restrict__ pooled)
{
  __shared__ unsigned short t1[204 * 130];   // bf16, 53 KB
  __shared__ unsigned short zbuf[64 * 130];  // bf16, 16.6 KB
  __shared__ float poolbuf[4 * 64];
  int blk = blockIdx.x;
  int b = blk >> 9;
  int tile = blk & 511;            // 64 (h) x 8 (w)
  int h0 = (tile >> 3) << 2;
  int w0 = (tile & 7) << 5;
  const float* wb = weff + b * WST;
  const float* inb = inp + (size_t)b * 64 * HW;
  int tid = threadIdx.x;
  int lane = tid & 63, wv = tid >> 6;

  if (tid < 204) {
    int p = tid;
    int hy = p / 34, hx = p - hy * 34;
    int h = h0 - 1 + hy, w = w0 - 1 + hx;
    if (h >= 0 && h < 256 && w >= 0 && w < 256) {
      const float* src = inb + h * 256 + w;
      float x[64];
      #pragma unroll
      for (int c = 0; c < 64; ++c) x[c] = src[c * HW];
      float s0=0,s1=0,q0=0,q1=0;
      #pragma unroll
      for (int c = 0; c < 64; c += 2) {
        s0 += x[c];   q0 += x[c]*x[c];
        s1 += x[c+1]; q1 += x[c+1]*x[c+1];
      }
      float mu  = (s0+s1) * (1.f/64.f);
      float inv = rsqrtf((q0+q1) * (1.f/64.f) - mu*mu + 1e-6f);
      #pragma unroll
      for (int c = 0; c < 64; ++c) x[c] = (x[c] - mu) * inv * ln1w[c] + ln1b[c];
      for (int j = 0; j < 128; ++j) {        // j wave-uniform -> scalar weight loads
        const float* wr = wb + j * 64;
        float a0=0,a1=0,a2=0,a3=0;
        #pragma unroll
        for (int c = 0; c < 64; c += 4) {
          a0 += wr[c]   * x[c];
          a1 += wr[c+1] * x[c+1];
          a2 += wr[c+2] * x[c+2];
          a3 += wr[c+3] * x[c+3];
        }
        t1[p * 130 + j] = f2bf(b1[j] + ((a0+a1)+(a2+a3)));
      }
    } else {
      for (int j = 0; j < 128; ++j) t1[p * 130 + j] = 0;  // zero padding (post-conv1)
    }
  }
  __syncthreads();

  // depthwise 3x3 + SimpleGate; lane = gated channel k, each wave does 32 pixels
  const float* w2e = wb + 8192;
  float wa[9], wc[9];
  #pragma unroll
  for (int i = 0; i < 9; ++i) { wa[i] = w2e[lane*9 + i]; wc[i] = w2e[(lane+64)*9 + i]; }
  float b2a = b2[lane], b2b = b2[lane + 64];
  float pacc = 0.f;
  for (int i = 0; i < 32; ++i) {
    int pp = wv * 32 + i;
    int ty = pp >> 5, tx = pp & 31;
    float a = b2a, bv = b2b;
    #pragma unroll
    for (int dy = 0; dy < 3; ++dy)
      #pragma unroll
      for (int dx = 0; dx < 3; ++dx) {
        int q = (ty + dy) * 34 + tx + dx;
        a  += wa[dy*3+dx] * bf2f(t1[q*130 + lane]);
        bv += wc[dy*3+dx] * bf2f(t1[q*130 + 64 + lane]);
      }
    float zv = a * bv;
    zbuf[lane * 130 + pp] = f2bf(zv);
    pacc += zv;
  }
  poolbuf[wv * 64 + lane] = pacc;
  __syncthreads();

  // coalesced bf16 z writeout (NCHW)
  unsigned short* zb = z + (size_t)b * 64 * HW;
  for (int e2 = tid; e2 < 8192; e2 += 256) {
    int k = e2 >> 7, pp = e2 & 127;
    int ty = pp >> 5, tx = pp & 31;
    zb[k * HW + (h0 + ty) * 256 + w0 + tx] = zbuf[k * 130 + pp];
  }
  if (tid < 64) {
    float ps = poolbuf[tid] + poolbuf[64 + tid] + poolbuf[128 + tid] + poolbuf[192 + tid];
    atomicAdd(&pooled[b * 64 + tid], ps);
  }
}

// ---------------- kernel 3: sca[b][k] = bsca + wsca_eff @ mean-pool ----------------
__global__ void k_sca(const float* __restrict__ bsca, const float* __restrict__ weff,
                      const float* __restrict__ pooled, float* __restrict__ sca)
{
  int b = blockIdx.x, k = threadIdx.x;   // 64 threads
  const float* wt = weff + b * WST + 9344;   // wscat [c][k]
  const float* pm = pooled + b * 64;
  float acc = bsca[k];
  for (int c = 0; c < 64; ++c) acc += wt[c * 64 + k] * (pm[c] * (1.f/65536.f));
  sca[b * 64 + k] = acc;
}

// ---------------- kernel 4: xsca -> conv3 -> +inp*beta -> LN2 -> conv4 -> gate -> conv5 ----
// thread = one pixel (one image row per block); weights wave-uniform -> scalar loads;
// runtime-indexed per-pixel vectors (yln, gate) live in a thread-private LDS column.
__global__ __launch_bounds__(256, 2) void k_stage2(
    const float* __restrict__ inp, const unsigned short* __restrict__ z,
    const float* __restrict__ sca, const float* __restrict__ ln2w, const float* __restrict__ ln2b,
    const float* __restrict__ b4, const float* __restrict__ weff, float* __restrict__ out)
{
  __shared__ float xbuf[64 * 256];   // 64 KB, column tid is thread-private
  int bh = blockIdx.x;
  int b = bh >> 8, h = bh & 255;
  int tid = threadIdx.x;
  const float* wb   = weff + b * WST;
  const float* w3bt = wb + 13440;
  const float* w4t  = wb + 17536;
  const float* w5gt = wb + 25728;
  const float* b3b  = wb + 29824;
  const float* b5g  = wb + 29888;
  const float* scb  = sca + b * 64;
  size_t base = (size_t)b * 64 * HW + (size_t)h * 256 + tid;
  const float* ip = inp + base;
  const unsigned short* zp = z + base;

  float y[64];
  #pragma unroll
  for (int c = 0; c < 64; ++c) y[c] = ip[c * HW] + b3b[c];
  // conv3 (accumulate into y; beta folded into weights/bias)
  for (int k0 = 0; k0 < 64; k0 += 8) {
    float xs[8];
    #pragma unroll
    for (int i = 0; i < 8; ++i) xs[i] = bf2f(zp[(k0+i) * HW]) * scb[k0+i];
    #pragma unroll
    for (int i = 0; i < 8; ++i) {
      const float* wr = w3bt + (k0+i) * 64;
      #pragma unroll
      for (int c = 0; c < 64; ++c) y[c] += wr[c] * xs[i];
    }
  }
  // LN2
  float s0=0,s1=0,q0=0,q1=0;
  #pragma unroll
  for (int c = 0; c < 64; c += 2) {
    s0 += y[c];   q0 += y[c]*y[c];
    s1 += y[c+1]; q1 += y[c+1]*y[c+1];
  }
  float mu  = (s0+s1) * (1.f/64.f);
  float inv = rsqrtf((q0+q1) * (1.f/64.f) - mu*mu + 1e-6f);
  #pragma unroll
  for (int c = 0; c < 64; ++c)
    xbuf[c * 256 + tid] = (y[c] - mu) * inv * ln2w[c] + ln2b[c];
  // conv4 (64 -> 128)
  float t4[128];
  #pragma unroll
  for (int j = 0; j < 128; ++j) t4[j] = b4[j];
  for (int cp = 0; cp < 64; ++cp) {
    float v = xbuf[cp * 256 + tid];
    const float* wr = w4t + cp * 128;
    #pragma unroll
    for (int j = 0; j < 128; ++j) t4[j] += wr[j] * v;
  }
  // SimpleGate -> store g in same LDS column (reads of yln are all done)
  #pragma unroll
  for (int k = 0; k < 64; ++k) xbuf[k * 256 + tid] = t4[k] * t4[64 + k];
  // conv5 (gamma folded), accumulate straight into y
  #pragma unroll
  for (int c = 0; c < 64; ++c) y[c] += b5g[c];
  for (int k = 0; k < 64; ++k) {
    float gv = xbuf[k * 256 + tid];
    const float* wr = w5gt + k * 64;
    #pragma unroll
    for (int c = 0; c < 64; ++c) y[c] += wr[c] * gv;
  }
  float* op = out + base;
  #pragma unroll
  for (int c = 0; c < 64; ++c) op[c * HW] = y[c];
}

extern "C" void kernel_launch(void* const* d_in, const int* in_sizes, int n_in,
                              void* d_out, int out_size, void* d_ws, size_t ws_size,
                              hipStream_t stream) {
  const float* inp   = (const float*)d_in[0];
  const float* probs = (const float*)d_in[1];
  const float* ln1w  = (const float*)d_in[2];
  const float* ln1b  = (const float*)d_in[3];
  const float* ln2w  = (const float*)d_in[4];
  const float* ln2b  = (const float*)d_in[5];
  const float* w1    = (const float*)d_in[6];
  const float* b1    = (const float*)d_in[7];
  const float* la1   = (const float*)d_in[8];
  const float* lb1   = (const float*)d_in[9];
  const float* w2    = (const float*)d_in[10];
  const float* b2    = (const float*)d_in[11];
  const float* la2   = (const float*)d_in[12];
  const float* lb2   = (const float*)d_in[13];
  const float* wsca  = (const float*)d_in[14];
  const float* bsca  = (const float*)d_in[15];
  const float* lasca = (const float*)d_in[16];
  const float* lbsca = (const float*)d_in[17];
  const float* w3    = (const float*)d_in[18];
  const float* b3    = (const float*)d_in[19];
  const float* la3   = (const float*)d_in[20];
  const float* lb3   = (const float*)d_in[21];
  const float* w4    = (const float*)d_in[22];
  const float* b4    = (const float*)d_in[23];
  const float* la4   = (const float*)d_in[24];
  const float* lb4   = (const float*)d_in[25];
  const float* w5    = (const float*)d_in[26];
  const float* b5    = (const float*)d_in[27];
  const float* la5   = (const float*)d_in[28];
  const float* lb5   = (const float*)d_in[29];
  const float* beta  = (const float*)d_in[30];
  const float* gamma = (const float*)d_in[31];
  float* ws = (float*)d_ws;
  float* weff   = ws;                 // 4 * 29952 floats
  float* pooled = ws + 119808;        // 256 floats (must be zeroed: ws is poisoned)
  float* scap   = ws + 120064;        // 256 floats
  unsigned short* zws = (unsigned short*)((char*)d_ws + 524288);  // bf16 z, 33.5 MB
  float* outp = (float*)d_out;

  hipMemsetAsync(pooled, 0, 256 * sizeof(float), stream);
  k_weights<<<dim3(4), dim3(256), 0, stream>>>(probs,
      w1, la1, lb1, w2, la2, lb2, wsca, lasca, lbsca,
      w3, la3, lb3, w4, la4, lb4, w5, la5, lb5,
      b3, b5, beta, gamma, weff);
  k_stage1<<<dim3(2048), dim3(256), 0, stream>>>(inp, ln1w, ln1b, b1, b2, weff, zws, pooled);
  k_sca<<<dim3(4), dim3(64), 0, stream>>>(bsca, weff, pooled, scap);
  k_stage2<<<dim3(1024), dim3(256), 0, stream>>>(inp, zws, scap, ln2w, ln2b, b4, weff, outp);
}

// Round 2
// 443.980 us; speedup vs baseline: 1.6095x; 1.6095x over previous
//
#include <hip/hip_runtime.h>
#include <hip/hip_bf16.h>

#define HW 65536
#define WST 29952   // per-sample fp32 effective-weight stride (floats)

typedef unsigned short U16;
typedef __attribute__((ext_vector_type(8))) short short8;
typedef __attribute__((ext_vector_type(4))) unsigned short us4;
typedef __attribute__((ext_vector_type(4))) float float4v;

// ws byte offsets
#define WEFF_OFF 0
#define FRAG_OFF 524288        // U16[4][24576]: w1f@0, w3f@8192, w4f@12288, w5f@20480
#define POOL_OFF 786432        // float[256]
#define SCA_OFF  787456        // float[256]
#define T1_OFF   1048576       // U16[4][128][HW]
#define Z_OFF    68157440      // U16[4][64][HW]

__device__ inline U16 f2bf(float f) {
  union { float f; unsigned u; } v; v.f = f;
  unsigned r = v.u + 0x7FFF + ((v.u >> 16) & 1);   // RNE
  return (U16)(r >> 16);
}
__device__ inline float bf2f(U16 h) {
  union { unsigned u; float f; } v; v.u = ((unsigned)h) << 16;
  return v.f;
}
__device__ inline float asfhi(unsigned u) {   // high bf16 of dword
  union { unsigned u; float f; } v; v.u = u & 0xffff0000u; return v.f;
}
__device__ inline float asflo(unsigned u) {   // low bf16 of dword
  union { unsigned u; float f; } v; v.u = u << 16; return v.f;
}

// ---------------- kernel 1: per-sample effective weights + bf16 MFMA B-fragments ----
__global__ void k_weights(const float* __restrict__ probs,
    const float* __restrict__ w1, const float* __restrict__ la1, const float* __restrict__ lb1,
    const float* __restrict__ w2, const float* __restrict__ la2, const float* __restrict__ lb2,
    const float* __restrict__ wsca, const float* __restrict__ lasca, const float* __restrict__ lbsca,
    const float* __restrict__ w3, const float* __restrict__ la3, const float* __restrict__ lb3,
    const float* __restrict__ w4, const float* __restrict__ la4, const float* __restrict__ lb4,
    const float* __restrict__ w5, const float* __restrict__ la5, const float* __restrict__ lb5,
    const float* __restrict__ b3, const float* __restrict__ b5,
    const float* __restrict__ beta, const float* __restrict__ gamma,
    float* __restrict__ weff, U16* __restrict__ fragw)
{
  int b = blockIdx.x, tid = threadIdx.x;
  float p0 = probs[b*3+0], p1 = probs[b*3+1], p2 = probs[b*3+2];
  int e = 0; float g = p0;
  if (p1 > g) { g = p1; e = 1; }
  if (p2 > g) { g = p2; e = 2; }
  float s = 2.0f * g;               // SCALING * gate
  float* wb = weff + b * WST;
  for (int idx = tid; idx < 8192; idx += 256) {     // w1e [j][c]  @0
    int j = idx >> 6, c = idx & 63;
    float acc = w1[idx];
    #pragma unroll
    for (int r = 0; r < 4; ++r)
      acc += s * lb1[(e*128 + j)*4 + r] * la1[(e*4 + r)*64 + c];
    wb[idx] = acc;
  }
  for (int idx = tid; idx < 1152; idx += 256) {     // w2e [j][3x3] @8192
    int row = idx / 3, dx = idx - row*3;
    float acc = w2[idx];
    #pragma unroll
    for (int r = 0; r < 12; ++r)
      acc += s * lb2[e*4608 + row*12 + r] * la2[e*36 + r*3 + dx];
    wb[8192 + idx] = acc;
  }
  for (int idx = tid; idx < 4096; idx += 256) {     // wscat [c][k] @9344
    int c = idx >> 6, k = idx & 63;
    float acc = wsca[k*64 + c];
    #pragma unroll
    for (int r = 0; r < 4; ++r)
      acc += s * lbsca[(e*64 + k)*4 + r] * lasca[(e*4 + r)*64 + c];
    wb[9344 + idx] = acc;
  }
  for (int idx = tid; idx < 4096; idx += 256) {     // w3bt [k][c] (T, beta-folded) @13440
    int k = idx >> 6, c = idx & 63;
    float acc = w3[c*64 + k];
    #pragma unroll
    for (int r = 0; r < 4; ++r)
      acc += s * lb3[(e*64 + c)*4 + r] * la3[(e*4 + r)*64 + k];
    wb[13440 + idx] = acc * beta[c];
  }
  for (int idx = tid; idx < 8192; idx += 256) {     // w4t [cp][j] (T) @17536
    int cp = idx >> 7, j = idx & 127;
    float acc = w4[j*64 + cp];
    #pragma unroll
    for (int r = 0; r < 4; ++r)
      acc += s * lb4[(e*128 + j)*4 + r] * la4[(e*4 + r)*64 + cp];
    wb[17536 + idx] = acc;
  }
  for (int idx = tid; idx < 4096; idx += 256) {     // w5gt [k][c] (T, gamma-folded) @25728
    int k = idx >> 6, c = idx & 63;
    float acc = w5[c*64 + k];
    #pragma unroll
    for (int r = 0; r < 4; ++r)
      acc += s * lb5[(e*64 + c)*4 + r] * la5[(e*4 + r)*64 + k];
    wb[25728 + idx] = acc * gamma[c];
  }
  if (tid < 64) {
    wb[29824 + tid] = b3[tid] * beta[tid];   // beta-folded b3
    wb[29888 + tid] = b5[tid] * gamma[tid];  // gamma-folded b5
  }
  __syncthreads();   // weff visible to block (global, same block => visible after barrier)

  // ---- pack bf16 B-fragments: lane l holds B[k = s*32 + (l>>4)*8 + j][n = nt*16 + (l&15)]
  U16* fws = fragw + b * 24576;
  for (int idx = tid; idx < 8192; idx += 256) {     // w1f: B[k=c][n=j] = w1e[n][k]
    int j = idx & 7, l = (idx >> 3) & 63, s2 = (idx >> 9) & 1, nt = idx >> 10;
    int n = nt*16 + (l & 15), k = s2*32 + ((l >> 4) << 3) + j;
    fws[idx] = f2bf(wb[n*64 + k]);
  }
  for (int idx = tid; idx < 4096; idx += 256) {     // w3f: B = w3bt [k][n]
    int j = idx & 7, l = (idx >> 3) & 63, s2 = (idx >> 9) & 1, nt = idx >> 10;
    int n = nt*16 + (l & 15), k = s2*32 + ((l >> 4) << 3) + j;
    fws[8192 + idx] = f2bf(wb[13440 + k*64 + n]);
  }
  for (int idx = tid; idx < 8192; idx += 256) {     // w4f: B = w4t [k][n], N=128
    int j = idx & 7, l = (idx >> 3) & 63, s2 = (idx >> 9) & 1, nt = idx >> 10;
    int n = nt*16 + (l & 15), k = s2*32 + ((l >> 4) << 3) + j;
    fws[12288 + idx] = f2bf(wb[17536 + k*128 + n]);
  }
  for (int idx = tid; idx < 4096; idx += 256) {     // w5f: B = w5gt [k][n]
    int j = idx & 7, l = (idx >> 3) & 63, s2 = (idx >> 9) & 1, nt = idx >> 10;
    int n = nt*16 + (l & 15), k = s2*32 + ((l >> 4) << 3) + j;
    fws[20480 + idx] = f2bf(wb[25728 + k*64 + n]);
  }
}

// ---------------- kernel 2: LN1 + conv1 (1x1, 64->128) via MFMA; t1 -> ws bf16 NCHW ----
// block = (b, h): one image row, M=256 px, N=128, K=64.
__global__ __launch_bounds__(256, 2) void k_conv1(
    const float* __restrict__ inp, const float* __restrict__ ln1w, const float* __restrict__ ln1b,
    const float* __restrict__ b1, const U16* __restrict__ fragw, U16* __restrict__ t1)
{
  __shared__ __align__(16) U16 sm[16640];  // afrag 16384 (16 mt x 2 s x 64 l x 8), t1buf 64*260
  int blk = blockIdx.x;
  int b = blk >> 8, h = blk & 255;
  int tid = threadIdx.x, lane = tid & 63, w = tid >> 6;

  { // phase 1: LN1 per pixel, write A-fragments
    const float* src = inp + (size_t)b*64*HW + h*256 + tid;
    float x[64];
    #pragma unroll
    for (int c = 0; c < 64; ++c) x[c] = src[(size_t)c * HW];
    float s0=0,s1=0,q0=0,q1=0;
    #pragma unroll
    for (int c = 0; c < 64; c += 2) {
      s0 += x[c];   q0 += x[c]*x[c];
      s1 += x[c+1]; q1 += x[c+1]*x[c+1];
    }
    float mu  = (s0+s1) * (1.f/64.f);
    float inv = rsqrtf((q0+q1) * (1.f/64.f) - mu*mu + 1e-6f);
    #pragma unroll
    for (int c = 0; c < 64; ++c) x[c] = (x[c] - mu) * inv * ln1w[c] + ln1b[c];
    int mt = tid >> 4, m = tid & 15;
    #pragma unroll
    for (int s = 0; s < 2; ++s)
      #pragma unroll
      for (int q = 0; q < 4; ++q) {
        short8 v;
        #pragma unroll
        for (int j = 0; j < 8; ++j) v[j] = (short)f2bf(x[s*32 + q*8 + j]);
        *(short8*)&sm[mt*1024 + s*512 + (q*16 + m)*8] = v;
      }
  }
  __syncthreads();

  // phase 2: MFMA. wave w owns mt = 4w..4w+3, all 8 nt.
  const U16* fw = fragw + b * 24576;    // w1f
  short8 bw[16];
  #pragma unroll
  for (int i = 0; i < 16; ++i) bw[i] = *(const short8*)&fw[(i*64 + lane)*8];
  float4v acc[4][8];
  #pragma unroll
  for (int mi = 0; mi < 4; ++mi)
    #pragma unroll
    for (int nt = 0; nt < 8; ++nt) acc[mi][nt] = (float4v)(0.f);
  #pragma unroll
  for (int mi = 0; mi < 4; ++mi) {
    int mt = w*4 + mi;
    #pragma unroll
    for (int s = 0; s < 2; ++s) {
      short8 a = *(const short8*)&sm[mt*1024 + s*512 + lane*8];
      #pragma unroll
      for (int nt = 0; nt < 8; ++nt)
        acc[mi][nt] = __builtin_amdgcn_mfma_f32_16x16x32_bf16(a, bw[nt*2 + s], acc[mi][nt], 0, 0, 0);
    }
  }
  float b1v[8];
  #pragma unroll
  for (int nt = 0; nt < 8; ++nt) b1v[nt] = b1[nt*16 + (lane & 15)];
  __syncthreads();   // all afrag reads done before t1buf overwrite

  // phase 3: epilogue via LDS transpose, two 64-channel halves
  for (int half = 0; half < 2; ++half) {
    if (half) __syncthreads();
    #pragma unroll
    for (int mi = 0; mi < 4; ++mi) {
      int px0 = (w*4 + mi)*16 + ((lane >> 4) << 2);
      #pragma unroll
      for (int nt2 = 0; nt2 < 4; ++nt2) {
        int nt = half*4 + nt2;
        int jr = nt2*16 + (lane & 15);
        us4 pk;
        #pragma unroll
        for (int r = 0; r < 4; ++r) pk[r] = f2bf(acc[mi][nt][r] + b1v[nt]);
        *(us4*)&sm[jr*260 + px0] = pk;
      }
    }
    __syncthreads();
    U16* dst = t1 + ((size_t)(b*128 + half*64)) * HW + h*256;
    #pragma unroll 4
    for (int it = 0; it < 32; ++it) {
      int idx = it*256 + tid;
      int jr = idx >> 7, pp2 = (idx & 127) * 2;
      *(unsigned*)&dst[(size_t)jr * HW + pp2] = *(unsigned*)&sm[jr*260 + pp2];
    }
  }
}

// ---------------- kernel 3: depthwise 3x3 + SimpleGate -> z (bf16 NCHW) ----------------
// block = (b, row pair); thread handles 2 pixels.
__global__ __launch_bounds__(256, 2) void k_dwgate(
    const U16* __restrict__ t1, const float* __restrict__ weff, const float* __restrict__ b2,
    U16* __restrict__ z)
{
  int blk = blockIdx.x;
  int b = blk >> 7, hp = blk & 127;
  int tid = threadIdx.x;
  int h = hp*2 + (tid >> 7);          // wave-uniform row
  int px0 = (tid & 127) * 2;
  const float* w2e = weff + b*WST + 8192;
  const U16* tbase = t1 + (size_t)b*128*HW + (size_t)h*256 + px0;
  U16* zb = z + (size_t)b*64*HW + (size_t)h*256 + px0;
  bool okm = px0 > 0, okp = px0 < 254;
  for (int k = 0; k < 64; ++k) {
    const float* wa = w2e + k*9;
    const float* wc = w2e + (k+64)*9;
    float a0 = b2[k], a1 = a0;
    float c0 = b2[k+64], c1 = c0;
    const U16* ta = tbase + (size_t)k * HW;
    const U16* tc = ta + (size_t)64 * HW;
    #pragma unroll
    for (int dy = 0; dy < 3; ++dy) {
      int hr = h - 1 + dy;
      if (hr < 0 || hr > 255) continue;
      int ro = (dy - 1) * 256;
      unsigned um = okm ? *(const unsigned*)(ta + ro - 2) : 0u;
      unsigned uc = *(const unsigned*)(ta + ro);
      unsigned up = okp ? *(const unsigned*)(ta + ro + 2) : 0u;
      float xm1 = asfhi(um), x0 = asflo(uc), x1 = asfhi(uc), x2 = asflo(up);
      a0 += wa[dy*3]*xm1 + wa[dy*3+1]*x0 + wa[dy*3+2]*x1;
      a1 += wa[dy*3]*x0  + wa[dy*3+1]*x1 + wa[dy*3+2]*x2;
      um = okm ? *(const unsigned*)(tc + ro - 2) : 0u;
      uc = *(const unsigned*)(tc + ro);
      up = okp ? *(const unsigned*)(tc + ro + 2) : 0u;
      xm1 = asfhi(um); x0 = asflo(uc); x1 = asfhi(uc); x2 = asflo(up);
      c0 += wc[dy*3]*xm1 + wc[dy*3+1]*x0 + wc[dy*3+2]*x1;
      c1 += wc[dy*3]*x0  + wc[dy*3+1]*x1 + wc[dy*3+2]*x2;
    }
    float z0 = a0*c0, z1 = a1*c1;
    unsigned pz = (unsigned)f2bf(z0) | ((unsigned)f2bf(z1) << 16);
    *(unsigned*)(zb + (size_t)k * HW) = pz;
  }
}

// ---------------- kernel 4: pool over H*W per (b,k) ----------------
__global__ void k_pool(const U16* __restrict__ z, float* __restrict__ pooled)
{
  __shared__ float red[256];
  int b = blockIdx.x >> 6, k = blockIdx.x & 63;
  int tid = threadIdx.x;
  const unsigned* zp = (const unsigned*)(z + ((size_t)(b*64 + k)) * HW);
  float s = 0.f;
  for (int it = 0; it < 128; ++it) {
    unsigned u = zp[it*256 + tid];
    s += asflo(u) + asfhi(u);
  }
  red[tid] = s;
  __syncthreads();
  for (int st = 128; st >= 1; st >>= 1) {
    if (tid < st) red[tid] += red[tid + st];
    __syncthreads();
  }
  if (tid == 0) pooled[b*64 + k] = red[0];
}

// ---------------- kernel 5: sca[b][k] ----------------
__global__ void k_sca(const float* __restrict__ bsca, const float* __restrict__ weff,
                      const float* __restrict__ pooled, float* __restrict__ sca)
{
  int b = blockIdx.x, k = threadIdx.x;   // 64 threads
  const float* wt = weff + b * WST + 9344;   // wscat [c][k]
  const float* pm = pooled + b * 64;
  float acc = bsca[k];
  for (int c = 0; c < 64; ++c) acc += wt[c * 64 + k] * (pm[c] * (1.f/65536.f));
  sca[b * 64 + k] = acc;
}

// ---------------- kernel 6: xsca -> conv3 -> +inp (beta folded) -> LN2 -> conv4 -> gate -> conv5 ----
// block = (b, h): one image row. MFMA for conv3/conv4/conv5; per-pixel ops via LDS round-trips.
__global__ __launch_bounds__(256, 2) void k_stage2(
    const float* __restrict__ inp, const U16* __restrict__ z, const float* __restrict__ sca,
    const float* __restrict__ ln2w, const float* __restrict__ ln2b, const float* __restrict__ b4,
    const float* __restrict__ weff, const U16* __restrict__ fragw, float* __restrict__ out)
{
  __shared__ __align__(16) U16 yb[256*72];      // y, bf16, stride 72
  __shared__ __align__(16) char afr[34816];     // afrag U16[16384] / afragF float[256*33]
  U16* afrag = (U16*)afr;
  float* afragF = (float*)afr;
  int blk = blockIdx.x;
  int b = blk >> 8, h = blk & 255;
  int tid = threadIdx.x, lane = tid & 63, w = tid >> 6;
  const float* wb = weff + b * WST;
  const U16* fw = fragw + b * 24576;

  float y0[64];
  { // phase A: xs = z*sca -> A-frags; y0 = inp row
    const U16* zp = z + (size_t)b*64*HW + h*256 + tid;
    const float* scb = sca + b*64;
    float xs[64];
    #pragma unroll
    for (int k = 0; k < 64; ++k) xs[k] = bf2f(zp[(size_t)k * HW]) * scb[k];
    int mt = tid >> 4, m = tid & 15;
    #pragma unroll
    for (int s = 0; s < 2; ++s)
      #pragma unroll
      for (int q = 0; q < 4; ++q) {
        short8 v;
        #pragma unroll
        for (int j = 0; j < 8; ++j) v[j] = (short)f2bf(xs[s*32 + q*8 + j]);
        *(short8*)&afrag[mt*1024 + s*512 + (q*16 + m)*8] = v;
      }
    const float* ip = inp + (size_t)b*64*HW + h*256 + tid;
    #pragma unroll
    for (int c = 0; c < 64; ++c) y0[c] = ip[(size_t)c * HW];
  }
  __syncthreads();

  { // conv3: [256x64] @ w3bt[64x64] -> yb (bf16, pre-residual)
    short8 bw3[8];
    #pragma unroll
    for (int i = 0; i < 8; ++i) bw3[i] = *(const short8*)&fw[8192 + (i*64 + lane)*8];
    float4v acc[4][4];
    #pragma unroll
    for (int mi = 0; mi < 4; ++mi)
      #pragma unroll
      for (int nt = 0; nt < 4; ++nt) acc[mi][nt] = (float4v)(0.f);
    #pragma unroll
    for (int mi = 0; mi < 4; ++mi) {
      int mt = w*4 + mi;
      #pragma unroll
      for (int s = 0; s < 2; ++s) {
        short8 a = *(const short8*)&afrag[mt*1024 + s*512 + lane*8];
        #pragma unroll
        for (int nt = 0; nt < 4; ++nt)
          acc[mi][nt] = __builtin_amdgcn_mfma_f32_16x16x32_bf16(a, bw3[nt*2 + s], acc[mi][nt], 0, 0, 0);
      }
    }
    #pragma unroll
    for (int mi = 0; mi < 4; ++mi) {
      int pxb = (w*4 + mi)*16 + ((lane >> 4) << 2);
      #pragma unroll
      for (int nt = 0; nt < 4; ++nt) {
        int c = nt*16 + (lane & 15);
        #pragma unroll
        for (int r = 0; r < 4; ++r)
          yb[(pxb + r)*72 + c] = f2bf(acc[mi][nt][r]);
      }
    }
  }
  __syncthreads();

  { // phase C (thread = pixel): residual + LN2 -> xln A-frags; write y back (bf16)
    const float* b3b = wb + 29824;
    float y[64];
    #pragma unroll
    for (int c8 = 0; c8 < 8; ++c8) {
      short8 v = *(const short8*)&yb[tid*72 + c8*8];
      #pragma unroll
      for (int j = 0; j < 8; ++j) y[c8*8 + j] = bf2f((U16)v[j]);
    }
    #pragma unroll
    for (int c = 0; c < 64; ++c) y[c] += y0[c] + b3b[c];
    float s0=0,s1=0,q0=0,q1=0;
    #pragma unroll
    for (int c = 0; c < 64; c += 2) {
      s0 += y[c];   q0 += y[c]*y[c];
      s1 += y[c+1]; q1 += y[c+1]*y[c+1];
    }
    float mu  = (s0+s1) * (1.f/64.f);
    float inv = rsqrtf((q0+q1) * (1.f/64.f) - mu*mu + 1e-6f);
    int mt = tid >> 4, m = tid & 15;
    #pragma unroll
    for (int s = 0; s < 2; ++s)
      #pragma unroll
      for (int q = 0; q < 4; ++q) {
        short8 v;
        #pragma unroll
        for (int j = 0; j < 8; ++j) {
          int c = s*32 + q*8 + j;
          v[j] = (short)f2bf((y[c] - mu) * inv * ln2w[c] + ln2b[c]);
        }
        *(short8*)&afrag[mt*1024 + s*512 + (q*16 + m)*8] = v;
      }
    #pragma unroll
    for (int c8 = 0; c8 < 8; ++c8) {
      short8 v;
      #pragma unroll
      for (int j = 0; j < 8; ++j) v[j] = (short)f2bf(y[c8*8 + j]);
      *(short8*)&yb[tid*72 + c8*8] = v;
    }
  }
  __syncthreads();

  float4v acc5[4][4];
  { // conv4 (64->128) + in-register SimpleGate -> g A-frags (own-wave region) -> conv5
    short8 bw4[16];
    #pragma unroll
    for (int i = 0; i < 16; ++i) bw4[i] = *(const short8*)&fw[12288 + (i*64 + lane)*8];
    float b4a[8];
    #pragma unroll
    for (int nt = 0; nt < 8; ++nt) b4a[nt] = b4[nt*16 + (lane & 15)];
    float4v acc[4][8];
    #pragma unroll
    for (int mi = 0; mi < 4; ++mi)
      #pragma unroll
      for (int nt = 0; nt < 8; ++nt) acc[mi][nt] = (float4v)(0.f);
    #pragma unroll
    for (int mi = 0; mi < 4; ++mi) {
      int mt = w*4 + mi;
      #pragma unroll
      for (int s = 0; s < 2; ++s) {
        short8 a = *(const short8*)&afrag[mt*1024 + s*512 + lane*8];
        #pragma unroll
        for (int nt = 0; nt < 8; ++nt)
          acc[mi][nt] = __builtin_amdgcn_mfma_f32_16x16x32_bf16(a, bw4[nt*2 + s], acc[mi][nt], 0, 0, 0);
      }
    }
    // gate: t4[px][k] * t4[px][k+64] — same lane, same reg across nt / nt+4
    #pragma unroll
    for (int mi = 0; mi < 4; ++mi) {
      int mt = w*4 + mi;
      int mloc = ((lane >> 4) << 2);
      #pragma unroll
      for (int nt = 0; nt < 4; ++nt) {
        int k = nt*16 + (lane & 15);
        int s_ = k >> 5, q = (k >> 3) & 3, j = k & 7;
        #pragma unroll
        for (int r = 0; r < 4; ++r) {
          float gv = (acc[mi][nt][r] + b4a[nt]) * (acc[mi][nt+4][r] + b4a[nt+4]);
          afrag[mt*1024 + s_*512 + (q*16 + mloc + r)*8 + j] = f2bf(gv);
        }
      }
    }
    // conv5 reads only own-wave region (RAW within wave: no barrier needed)
    short8 bw5[8];
    #pragma unroll
    for (int i = 0; i < 8; ++i) bw5[i] = *(const short8*)&fw[20480 + (i*64 + lane)*8];
    #pragma unroll
    for (int mi = 0; mi < 4; ++mi)
      #pragma unroll
      for (int nt = 0; nt < 4; ++nt) acc5[mi][nt] = (float4v)(0.f);
    #pragma unroll
    for (int mi = 0; mi < 4; ++mi) {
      int mt = w*4 + mi;
      #pragma unroll
      for (int s = 0; s < 2; ++s) {
        short8 a = *(const short8*)&afrag[mt*1024 + s*512 + lane*8];
        #pragma unroll
        for (int nt = 0; nt < 4; ++nt)
          acc5[mi][nt] = __builtin_amdgcn_mfma_f32_16x16x32_bf16(a, bw5[nt*2 + s], acc5[mi][nt], 0, 0, 0);
      }
    }
  }
  __syncthreads();   // all afrag reads done before fp32 reuse (regions overlap across waves)

  { // epilogue: out = y + b5g + conv5, fp32, coalesced via LDS transpose (own-wave rows)
    const float* b5g = wb + 29888;
    float b5f[4];
    #pragma unroll
    for (int nt = 0; nt < 4; ++nt) b5f[nt] = b5g[nt*16 + (lane & 15)];
    float* op = out + (size_t)b*64*HW + h*256;
    for (int chalf = 0; chalf < 2; ++chalf) {
      #pragma unroll
      for (int mi = 0; mi < 4; ++mi) {
        int pxb = (w*4 + mi)*16 + ((lane >> 4) << 2);
        #pragma unroll
        for (int nt2 = 0; nt2 < 2; ++nt2) {
          int nt = chalf*2 + nt2;
          int c = nt*16 + (lane & 15);
          #pragma unroll
          for (int r = 0; r < 4; ++r) {
            float v = acc5[mi][nt][r] + b5f[nt] + bf2f(yb[(pxb + r)*72 + c]);
            afragF[(pxb + r)*33 + (c - chalf*32)] = v;
          }
        }
      }
      // own-wave rows: thread tid reads row tid (written by its own wave) — no barrier needed
      #pragma unroll 4
      for (int cc = 0; cc < 32; ++cc)
        op[(size_t)(chalf*32 + cc) * HW + tid] = afragF[tid*33 + cc];
    }
  }
}

extern "C" void kernel_launch(void* const* d_in, const int* in_sizes, int n_in,
                              void* d_out, int out_size, void* d_ws, size_t ws_size,
                              hipStream_t stream) {
  const float* inp   = (const float*)d_in[0];
  const float* probs = (const float*)d_in[1];
  const float* ln1w  = (const float*)d_in[2];
  const float* ln1b  = (const float*)d_in[3];
  const float* ln2w  = (const float*)d_in[4];
  const float* ln2b  = (const float*)d_in[5];
  const float* w1    = (const float*)d_in[6];
  const float* b1    = (const float*)d_in[7];
  const float* la1   = (const float*)d_in[8];
  const float* lb1   = (const float*)d_in[9];
  const float* w2    = (const float*)d_in[10];
  const float* b2    = (const float*)d_in[11];
  const float* la2   = (const float*)d_in[12];
  const float* lb2   = (const float*)d_in[13];
  const float* wsca  = (const float*)d_in[14];
  const float* bsca  = (const float*)d_in[15];
  const float* lasca = (const float*)d_in[16];
  const float* lbsca = (const float*)d_in[17];
  const float* w3    = (const float*)d_in[18];
  const float* b3    = (const float*)d_in[19];
  const float* la3   = (const float*)d_in[20];
  const float* lb3   = (const float*)d_in[21];
  const float* w4    = (const float*)d_in[22];
  const float* b4    = (const float*)d_in[23];
  const float* la4   = (const float*)d_in[24];
  const float* lb4   = (const float*)d_in[25];
  const float* w5    = (const float*)d_in[26];
  const float* b5    = (const float*)d_in[27];
  const float* la5   = (const float*)d_in[28];
  const float* lb5   = (const float*)d_in[29];
  const float* beta  = (const float*)d_in[30];
  const float* gamma = (const float*)d_in[31];

  char* wsb = (char*)d_ws;
  float* weff   = (float*)(wsb + WEFF_OFF);
  U16*   fragw  = (U16*)(wsb + FRAG_OFF);
  float* pooled = (float*)(wsb + POOL_OFF);
  float* scap   = (float*)(wsb + SCA_OFF);
  U16*   t1     = (U16*)(wsb + T1_OFF);
  U16*   zws    = (U16*)(wsb + Z_OFF);
  float* outp   = (float*)d_out;

  k_weights<<<dim3(4), dim3(256), 0, stream>>>(probs,
      w1, la1, lb1, w2, la2, lb2, wsca, lasca, lbsca,
      w3, la3, lb3, w4, la4, lb4, w5, la5, lb5,
      b3, b5, beta, gamma, weff, fragw);
  k_conv1<<<dim3(1024), dim3(256), 0, stream>>>(inp, ln1w, ln1b, b1, fragw, t1);
  k_dwgate<<<dim3(512), dim3(256), 0, stream>>>(t1, weff, b2, zws);
  k_pool<<<dim3(256), dim3(256), 0, stream>>>(zws, pooled);
  k_sca<<<dim3(4), dim3(64), 0, stream>>>(bsca, weff, pooled, scap);
  k_stage2<<<dim3(1024), dim3(256), 0, stream>>>(inp, zws, scap, ln2w, ln2b, b4, weff, fragw, outp);
}

// Round 3
// 325.195 us; speedup vs baseline: 2.1974x; 1.3653x over previous
//
#include <hip/hip_runtime.h>
#include <hip/hip_bf16.h>

#define HW 65536
#define WST 29952   // per-sample fp32 effective-weight stride (floats)

typedef unsigned short U16;
typedef __attribute__((ext_vector_type(8))) short short8;
typedef __attribute__((ext_vector_type(4))) unsigned short us4;
typedef __attribute__((ext_vector_type(4))) float float4v;

// ws byte offsets
#define WEFF_OFF 0
#define FRAG_OFF 524288        // U16[4][24576]: w1f@0, w3f@8192, w4f@12288, w5f@20480
#define POOL_OFF 786432        // float[256]
#define SCA_OFF  787456        // float[256]
#define T1_OFF   1048576       // U16[4][128][HW]
#define Z_OFF    68157440      // U16[4][64][HW]

__device__ inline U16 f2bf(float f) {
  union { float f; unsigned u; } v; v.f = f;
  unsigned r = v.u + 0x7FFF + ((v.u >> 16) & 1);   // RNE
  return (U16)(r >> 16);
}
__device__ inline float bf2f(U16 h) {
  union { unsigned u; float f; } v; v.u = ((unsigned)h) << 16;
  return v.f;
}
__device__ inline float asfhi(unsigned u) {   // high bf16 of dword
  union { unsigned u; float f; } v; v.u = u & 0xffff0000u; return v.f;
}
__device__ inline float asflo(unsigned u) {   // low bf16 of dword
  union { unsigned u; float f; } v; v.u = u << 16; return v.f;
}

// ---------------- kernel 1: per-sample effective weights + bf16 MFMA B-fragments ----
__global__ void k_weights(const float* __restrict__ probs,
    const float* __restrict__ w1, const float* __restrict__ la1, const float* __restrict__ lb1,
    const float* __restrict__ w2, const float* __restrict__ la2, const float* __restrict__ lb2,
    const float* __restrict__ wsca, const float* __restrict__ lasca, const float* __restrict__ lbsca,
    const float* __restrict__ w3, const float* __restrict__ la3, const float* __restrict__ lb3,
    const float* __restrict__ w4, const float* __restrict__ la4, const float* __restrict__ lb4,
    const float* __restrict__ w5, const float* __restrict__ la5, const float* __restrict__ lb5,
    const float* __restrict__ b3, const float* __restrict__ b5,
    const float* __restrict__ beta, const float* __restrict__ gamma,
    float* __restrict__ weff, U16* __restrict__ fragw)
{
  int b = blockIdx.x, tid = threadIdx.x;
  float p0 = probs[b*3+0], p1 = probs[b*3+1], p2 = probs[b*3+2];
  int e = 0; float g = p0;
  if (p1 > g) { g = p1; e = 1; }
  if (p2 > g) { g = p2; e = 2; }
  float s = 2.0f * g;               // SCALING * gate
  float* wb = weff + b * WST;
  for (int idx = tid; idx < 8192; idx += 256) {     // w1e [j][c]  @0
    int j = idx >> 6, c = idx & 63;
    float acc = w1[idx];
    #pragma unroll
    for (int r = 0; r < 4; ++r)
      acc += s * lb1[(e*128 + j)*4 + r] * la1[(e*4 + r)*64 + c];
    wb[idx] = acc;
  }
  for (int idx = tid; idx < 1152; idx += 256) {     // w2e [j][3x3] @8192
    int row = idx / 3, dx = idx - row*3;
    float acc = w2[idx];
    #pragma unroll
    for (int r = 0; r < 12; ++r)
      acc += s * lb2[e*4608 + row*12 + r] * la2[e*36 + r*3 + dx];
    wb[8192 + idx] = acc;
  }
  for (int idx = tid; idx < 4096; idx += 256) {     // wscat [c][k] @9344
    int c = idx >> 6, k = idx & 63;
    float acc = wsca[k*64 + c];
    #pragma unroll
    for (int r = 0; r < 4; ++r)
      acc += s * lbsca[(e*64 + k)*4 + r] * lasca[(e*4 + r)*64 + c];
    wb[9344 + idx] = acc;
  }
  for (int idx = tid; idx < 4096; idx += 256) {     // w3bt [k][c] (T, beta-folded) @13440
    int k = idx >> 6, c = idx & 63;
    float acc = w3[c*64 + k];
    #pragma unroll
    for (int r = 0; r < 4; ++r)
      acc += s * lb3[(e*64 + c)*4 + r] * la3[(e*4 + r)*64 + k];
    wb[13440 + idx] = acc * beta[c];
  }
  for (int idx = tid; idx < 8192; idx += 256) {     // w4t [cp][j] (T) @17536
    int cp = idx >> 7, j = idx & 127;
    float acc = w4[j*64 + cp];
    #pragma unroll
    for (int r = 0; r < 4; ++r)
      acc += s * lb4[(e*128 + j)*4 + r] * la4[(e*4 + r)*64 + cp];
    wb[17536 + idx] = acc;
  }
  for (int idx = tid; idx < 4096; idx += 256) {     // w5gt [k][c] (T, gamma-folded) @25728
    int k = idx >> 6, c = idx & 63;
    float acc = w5[c*64 + k];
    #pragma unroll
    for (int r = 0; r < 4; ++r)
      acc += s * lb5[(e*64 + c)*4 + r] * la5[(e*4 + r)*64 + k];
    wb[25728 + idx] = acc * gamma[c];
  }
  if (tid < 64) {
    wb[29824 + tid] = b3[tid] * beta[tid];   // beta-folded b3
    wb[29888 + tid] = b5[tid] * gamma[tid];  // gamma-folded b5
  }
  __syncthreads();   // weff visible to block (global, same block => visible after barrier)

  // ---- pack bf16 B-fragments: lane l holds B[k = s*32 + (l>>4)*8 + j][n = nt*16 + (l&15)]
  U16* fws = fragw + b * 24576;
  for (int idx = tid; idx < 8192; idx += 256) {     // w1f: B[k=c][n=j] = w1e[n][k]
    int j = idx & 7, l = (idx >> 3) & 63, s2 = (idx >> 9) & 1, nt = idx >> 10;
    int n = nt*16 + (l & 15), k = s2*32 + ((l >> 4) << 3) + j;
    fws[idx] = f2bf(wb[n*64 + k]);
  }
  for (int idx = tid; idx < 4096; idx += 256) {     // w3f: B = w3bt [k][n]
    int j = idx & 7, l = (idx >> 3) & 63, s2 = (idx >> 9) & 1, nt = idx >> 10;
    int n = nt*16 + (l & 15), k = s2*32 + ((l >> 4) << 3) + j;
    fws[8192 + idx] = f2bf(wb[13440 + k*64 + n]);
  }
  for (int idx = tid; idx < 8192; idx += 256) {     // w4f: B = w4t [k][n], N=128
    int j = idx & 7, l = (idx >> 3) & 63, s2 = (idx >> 9) & 1, nt = idx >> 10;
    int n = nt*16 + (l & 15), k = s2*32 + ((l >> 4) << 3) + j;
    fws[12288 + idx] = f2bf(wb[17536 + k*128 + n]);
  }
  for (int idx = tid; idx < 4096; idx += 256) {     // w5f: B = w5gt [k][n]
    int j = idx & 7, l = (idx >> 3) & 63, s2 = (idx >> 9) & 1, nt = idx >> 10;
    int n = nt*16 + (l & 15), k = s2*32 + ((l >> 4) << 3) + j;
    fws[20480 + idx] = f2bf(wb[25728 + k*64 + n]);
  }
}

// ---------------- kernel 2: LN1 + conv1 (1x1, 64->128) via MFMA; t1 -> ws bf16 NCHW ----
// block = (b, h): one image row, M=256 px, N=128, K=64.
__global__ __launch_bounds__(256, 2) void k_conv1(
    const float* __restrict__ inp, const float* __restrict__ ln1w, const float* __restrict__ ln1b,
    const float* __restrict__ b1, const U16* __restrict__ fragw, U16* __restrict__ t1)
{
  __shared__ __align__(16) U16 sm[16640];  // afrag 16384 (16 mt x 2 s x 64 l x 8), t1buf 64*260
  int blk = blockIdx.x;
  int b = blk >> 8, h = blk & 255;
  int tid = threadIdx.x, lane = tid & 63, w = tid >> 6;

  { // phase 1: LN1 per pixel, write A-fragments
    const float* src = inp + (size_t)b*64*HW + h*256 + tid;
    float x[64];
    #pragma unroll
    for (int c = 0; c < 64; ++c) x[c] = src[(size_t)c * HW];
    float s0=0,s1=0,q0=0,q1=0;
    #pragma unroll
    for (int c = 0; c < 64; c += 2) {
      s0 += x[c];   q0 += x[c]*x[c];
      s1 += x[c+1]; q1 += x[c+1]*x[c+1];
    }
    float mu  = (s0+s1) * (1.f/64.f);
    float inv = rsqrtf((q0+q1) * (1.f/64.f) - mu*mu + 1e-6f);
    #pragma unroll
    for (int c = 0; c < 64; ++c) x[c] = (x[c] - mu) * inv * ln1w[c] + ln1b[c];
    int mt = tid >> 4, m = tid & 15;
    #pragma unroll
    for (int s = 0; s < 2; ++s)
      #pragma unroll
      for (int q = 0; q < 4; ++q) {
        short8 v;
        #pragma unroll
        for (int j = 0; j < 8; ++j) v[j] = (short)f2bf(x[s*32 + q*8 + j]);
        *(short8*)&sm[mt*1024 + s*512 + (q*16 + m)*8] = v;
      }
  }
  __syncthreads();

  // phase 2: MFMA. wave w owns mt = 4w..4w+3, all 8 nt.
  const U16* fw = fragw + b * 24576;    // w1f
  short8 bw[16];
  #pragma unroll
  for (int i = 0; i < 16; ++i) bw[i] = *(const short8*)&fw[(i*64 + lane)*8];
  float4v acc[4][8];
  #pragma unroll
  for (int mi = 0; mi < 4; ++mi)
    #pragma unroll
    for (int nt = 0; nt < 8; ++nt) acc[mi][nt] = (float4v)(0.f);
  #pragma unroll
  for (int mi = 0; mi < 4; ++mi) {
    int mt = w*4 + mi;
    #pragma unroll
    for (int s = 0; s < 2; ++s) {
      short8 a = *(const short8*)&sm[mt*1024 + s*512 + lane*8];
      #pragma unroll
      for (int nt = 0; nt < 8; ++nt)
        acc[mi][nt] = __builtin_amdgcn_mfma_f32_16x16x32_bf16(a, bw[nt*2 + s], acc[mi][nt], 0, 0, 0);
    }
  }
  float b1v[8];
  #pragma unroll
  for (int nt = 0; nt < 8; ++nt) b1v[nt] = b1[nt*16 + (lane & 15)];
  __syncthreads();   // all afrag reads done before t1buf overwrite

  // phase 3: epilogue via LDS transpose, two 64-channel halves
  for (int half = 0; half < 2; ++half) {
    if (half) __syncthreads();
    #pragma unroll
    for (int mi = 0; mi < 4; ++mi) {
      int px0 = (w*4 + mi)*16 + ((lane >> 4) << 2);
      #pragma unroll
      for (int nt2 = 0; nt2 < 4; ++nt2) {
        int nt = half*4 + nt2;
        int jr = nt2*16 + (lane & 15);
        us4 pk;
        #pragma unroll
        for (int r = 0; r < 4; ++r) pk[r] = f2bf(acc[mi][nt][r] + b1v[nt]);
        *(us4*)&sm[jr*260 + px0] = pk;
      }
    }
    __syncthreads();
    U16* dst = t1 + ((size_t)(b*128 + half*64)) * HW + h*256;
    #pragma unroll 4
    for (int it = 0; it < 32; ++it) {
      int idx = it*256 + tid;
      int jr = idx >> 7, pp2 = (idx & 127) * 2;
      *(unsigned*)&dst[(size_t)jr * HW + pp2] = *(unsigned*)&sm[jr*260 + pp2];
    }
  }
}

// ---------------- kernel 3: depthwise 3x3 + SimpleGate -> z (bf16 NCHW) ----------------
// block = (b, row-pair, kg): 16 gated channels per block, thread = 2 pixels.
// grid 2048 (8 blocks/CU) + explicit load-phase per channel for ILP.
__global__ __launch_bounds__(256) void k_dwgate(
    const U16* __restrict__ t1, const float* __restrict__ weff, const float* __restrict__ b2,
    U16* __restrict__ z)
{
  int blk = blockIdx.x;
  int kg = blk & 3;                   // channel group: 16 gated channels
  int hp = (blk >> 2) & 127;
  int b  = blk >> 9;
  int tid = threadIdx.x;
  int h = hp*2 + (tid >> 7);          // wave-uniform row
  int px0 = (tid & 127) * 2;
  const float* w2e = weff + b*WST + 8192;
  const U16* tbase = t1 + (size_t)b*128*HW + (size_t)h*256 + px0;
  U16* zb = z + (size_t)b*64*HW + (size_t)h*256 + px0;
  bool okm = px0 > 0, okp = px0 < 254;
  bool ok0 = h > 0, ok2 = h < 255;    // wave-uniform

  #pragma unroll 2
  for (int kk = 0; kk < 16; ++kk) {
    int k = kg*16 + kk;
    const U16* ta = tbase + (size_t)k * HW;
    const U16* tc = ta + (size_t)64 * HW;
    // ---- load phase: all 18 dwords issued before any compute ----
    unsigned La[9], Lc[9];
    #pragma unroll
    for (int dy = 0; dy < 3; ++dy) {
      bool okr = (dy == 0) ? ok0 : (dy == 2 ? ok2 : true);
      int ro = (dy - 1) * 256;
      La[dy*3+0] = (okr && okm) ? *(const unsigned*)(ta + ro - 2) : 0u;
      La[dy*3+1] =  okr         ? *(const unsigned*)(ta + ro)     : 0u;
      La[dy*3+2] = (okr && okp) ? *(const unsigned*)(ta + ro + 2) : 0u;
    }
    #pragma unroll
    for (int dy = 0; dy < 3; ++dy) {
      bool okr = (dy == 0) ? ok0 : (dy == 2 ? ok2 : true);
      int ro = (dy - 1) * 256;
      Lc[dy*3+0] = (okr && okm) ? *(const unsigned*)(tc + ro - 2) : 0u;
      Lc[dy*3+1] =  okr         ? *(const unsigned*)(tc + ro)     : 0u;
      Lc[dy*3+2] = (okr && okp) ? *(const unsigned*)(tc + ro + 2) : 0u;
    }
    // ---- compute phase ----
    const float* wa = w2e + k*9;            // wave-uniform -> s_load
    const float* wc = w2e + (k+64)*9;
    float a0 = b2[k], a1 = a0;
    float c0 = b2[k+64], c1 = c0;
    #pragma unroll
    for (int dy = 0; dy < 3; ++dy) {
      float xm1 = asfhi(La[dy*3+0]), x0 = asflo(La[dy*3+1]);
      float x1  = asfhi(La[dy*3+1]), x2 = asflo(La[dy*3+2]);
      a0 += wa[dy*3]*xm1 + wa[dy*3+1]*x0 + wa[dy*3+2]*x1;
      a1 += wa[dy*3]*x0  + wa[dy*3+1]*x1 + wa[dy*3+2]*x2;
      xm1 = asfhi(Lc[dy*3+0]); x0 = asflo(Lc[dy*3+1]);
      x1  = asfhi(Lc[dy*3+1]); x2 = asflo(Lc[dy*3+2]);
      c0 += wc[dy*3]*xm1 + wc[dy*3+1]*x0 + wc[dy*3+2]*x1;
      c1 += wc[dy*3]*x0  + wc[dy*3+1]*x1 + wc[dy*3+2]*x2;
    }
    unsigned pz = (unsigned)f2bf(a0*c0) | ((unsigned)f2bf(a1*c1) << 16);
    *(unsigned*)(zb + (size_t)k * HW) = pz;
  }
}

// ---------------- kernel 4: pool over H*W per (b,k) ----------------
__global__ void k_pool(const U16* __restrict__ z, float* __restrict__ pooled)
{
  __shared__ float red[256];
  int b = blockIdx.x >> 6, k = blockIdx.x & 63;
  int tid = threadIdx.x;
  const unsigned* zp = (const unsigned*)(z + ((size_t)(b*64 + k)) * HW);
  float s = 0.f;
  for (int it = 0; it < 128; ++it) {
    unsigned u = zp[it*256 + tid];
    s += asflo(u) + asfhi(u);
  }
  red[tid] = s;
  __syncthreads();
  for (int st = 128; st >= 1; st >>= 1) {
    if (tid < st) red[tid] += red[tid + st];
    __syncthreads();
  }
  if (tid == 0) pooled[b*64 + k] = red[0];
}

// ---------------- kernel 5: sca[b][k] ----------------
__global__ void k_sca(const float* __restrict__ bsca, const float* __restrict__ weff,
                      const float* __restrict__ pooled, float* __restrict__ sca)
{
  int b = blockIdx.x, k = threadIdx.x;   // 64 threads
  const float* wt = weff + b * WST + 9344;   // wscat [c][k]
  const float* pm = pooled + b * 64;
  float acc = bsca[k];
  for (int c = 0; c < 64; ++c) acc += wt[c * 64 + k] * (pm[c] * (1.f/65536.f));
  sca[b * 64 + k] = acc;
}

// ---------------- kernel 6: xsca -> conv3 -> +inp (beta folded) -> LN2 -> conv4 -> gate -> conv5 ----
// block = (b, h): one image row. MFMA for conv3/conv4/conv5; per-pixel ops via LDS round-trips.
__global__ __launch_bounds__(256, 2) void k_stage2(
    const float* __restrict__ inp, const U16* __restrict__ z, const float* __restrict__ sca,
    const float* __restrict__ ln2w, const float* __restrict__ ln2b, const float* __restrict__ b4,
    const float* __restrict__ weff, const U16* __restrict__ fragw, float* __restrict__ out)
{
  __shared__ __align__(16) U16 yb[256*72];      // y, bf16, stride 72
  __shared__ __align__(16) char afr[34816];     // afrag U16[16384] / afragF float[256*33]
  U16* afrag = (U16*)afr;
  float* afragF = (float*)afr;
  int blk = blockIdx.x;
  int b = blk >> 8, h = blk & 255;
  int tid = threadIdx.x, lane = tid & 63, w = tid >> 6;
  const float* wb = weff + b * WST;
  const U16* fw = fragw + b * 24576;

  float y0[64];
  { // phase A: xs = z*sca -> A-frags; y0 = inp row
    const U16* zp = z + (size_t)b*64*HW + h*256 + tid;
    const float* scb = sca + b*64;
    float xs[64];
    #pragma unroll
    for (int k = 0; k < 64; ++k) xs[k] = bf2f(zp[(size_t)k * HW]) * scb[k];
    int mt = tid >> 4, m = tid & 15;
    #pragma unroll
    for (int s = 0; s < 2; ++s)
      #pragma unroll
      for (int q = 0; q < 4; ++q) {
        short8 v;
        #pragma unroll
        for (int j = 0; j < 8; ++j) v[j] = (short)f2bf(xs[s*32 + q*8 + j]);
        *(short8*)&afrag[mt*1024 + s*512 + (q*16 + m)*8] = v;
      }
    const float* ip = inp + (size_t)b*64*HW + h*256 + tid;
    #pragma unroll
    for (int c = 0; c < 64; ++c) y0[c] = ip[(size_t)c * HW];
  }
  __syncthreads();

  { // conv3: [256x64] @ w3bt[64x64] -> yb (bf16, pre-residual)
    short8 bw3[8];
    #pragma unroll
    for (int i = 0; i < 8; ++i) bw3[i] = *(const short8*)&fw[8192 + (i*64 + lane)*8];
    float4v acc[4][4];
    #pragma unroll
    for (int mi = 0; mi < 4; ++mi)
      #pragma unroll
      for (int nt = 0; nt < 4; ++nt) acc[mi][nt] = (float4v)(0.f);
    #pragma unroll
    for (int mi = 0; mi < 4; ++mi) {
      int mt = w*4 + mi;
      #pragma unroll
      for (int s = 0; s < 2; ++s) {
        short8 a = *(const short8*)&afrag[mt*1024 + s*512 + lane*8];
        #pragma unroll
        for (int nt = 0; nt < 4; ++nt)
          acc[mi][nt] = __builtin_amdgcn_mfma_f32_16x16x32_bf16(a, bw3[nt*2 + s], acc[mi][nt], 0, 0, 0);
      }
    }
    #pragma unroll
    for (int mi = 0; mi < 4; ++mi) {
      int pxb = (w*4 + mi)*16 + ((lane >> 4) << 2);
      #pragma unroll
      for (int nt = 0; nt < 4; ++nt) {
        int c = nt*16 + (lane & 15);
        #pragma unroll
        for (int r = 0; r < 4; ++r)
          yb[(pxb + r)*72 + c] = f2bf(acc[mi][nt][r]);
      }
    }
  }
  __syncthreads();

  { // phase C (thread = pixel): residual + LN2 -> xln A-frags; write y back (bf16)
    const float* b3b = wb + 29824;
    float y[64];
    #pragma unroll
    for (int c8 = 0; c8 < 8; ++c8) {
      short8 v = *(const short8*)&yb[tid*72 + c8*8];
      #pragma unroll
      for (int j = 0; j < 8; ++j) y[c8*8 + j] = bf2f((U16)v[j]);
    }
    #pragma unroll
    for (int c = 0; c < 64; ++c) y[c] += y0[c] + b3b[c];
    float s0=0,s1=0,q0=0,q1=0;
    #pragma unroll
    for (int c = 0; c < 64; c += 2) {
      s0 += y[c];   q0 += y[c]*y[c];
      s1 += y[c+1]; q1 += y[c+1]*y[c+1];
    }
    float mu  = (s0+s1) * (1.f/64.f);
    float inv = rsqrtf((q0+q1) * (1.f/64.f) - mu*mu + 1e-6f);
    int mt = tid >> 4, m = tid & 15;
    #pragma unroll
    for (int s = 0; s < 2; ++s)
      #pragma unroll
      for (int q = 0; q < 4; ++q) {
        short8 v;
        #pragma unroll
        for (int j = 0; j < 8; ++j) {
          int c = s*32 + q*8 + j;
          v[j] = (short)f2bf((y[c] - mu) * inv * ln2w[c] + ln2b[c]);
        }
        *(short8*)&afrag[mt*1024 + s*512 + (q*16 + m)*8] = v;
      }
    #pragma unroll
    for (int c8 = 0; c8 < 8; ++c8) {
      short8 v;
      #pragma unroll
      for (int j = 0; j < 8; ++j) v[j] = (short)f2bf(y[c8*8 + j]);
      *(short8*)&yb[tid*72 + c8*8] = v;
    }
  }
  __syncthreads();

  float4v acc5[4][4];
  { // conv4 (64->128) + in-register SimpleGate -> g A-frags (own-wave region) -> conv5
    short8 bw4[16];
    #pragma unroll
    for (int i = 0; i < 16; ++i) bw4[i] = *(const short8*)&fw[12288 + (i*64 + lane)*8];
    float b4a[8];
    #pragma unroll
    for (int nt = 0; nt < 8; ++nt) b4a[nt] = b4[nt*16 + (lane & 15)];
    float4v acc[4][8];
    #pragma unroll
    for (int mi = 0; mi < 4; ++mi)
      #pragma unroll
      for (int nt = 0; nt < 8; ++nt) acc[mi][nt] = (float4v)(0.f);
    #pragma unroll
    for (int mi = 0; mi < 4; ++mi) {
      int mt = w*4 + mi;
      #pragma unroll
      for (int s = 0; s < 2; ++s) {
        short8 a = *(const short8*)&afrag[mt*1024 + s*512 + lane*8];
        #pragma unroll
        for (int nt = 0; nt < 8; ++nt)
          acc[mi][nt] = __builtin_amdgcn_mfma_f32_16x16x32_bf16(a, bw4[nt*2 + s], acc[mi][nt], 0, 0, 0);
      }
    }
    // gate: t4[px][k] * t4[px][k+64] — same lane, same reg across nt / nt+4
    #pragma unroll
    for (int mi = 0; mi < 4; ++mi) {
      int mt = w*4 + mi;
      int mloc = ((lane >> 4) << 2);
      #pragma unroll
      for (int nt = 0; nt < 4; ++nt) {
        int k = nt*16 + (lane & 15);
        int s_ = k >> 5, q = (k >> 3) & 3, j = k & 7;
        #pragma unroll
        for (int r = 0; r < 4; ++r) {
          float gv = (acc[mi][nt][r] + b4a[nt]) * (acc[mi][nt+4][r] + b4a[nt+4]);
          afrag[mt*1024 + s_*512 + (q*16 + mloc + r)*8 + j] = f2bf(gv);
        }
      }
    }
    // conv5 reads only own-wave region (RAW within wave: no barrier needed)
    short8 bw5[8];
    #pragma unroll
    for (int i = 0; i < 8; ++i) bw5[i] = *(const short8*)&fw[20480 + (i*64 + lane)*8];
    #pragma unroll
    for (int mi = 0; mi < 4; ++mi)
      #pragma unroll
      for (int nt = 0; nt < 4; ++nt) acc5[mi][nt] = (float4v)(0.f);
    #pragma unroll
    for (int mi = 0; mi < 4; ++mi) {
      int mt = w*4 + mi;
      #pragma unroll
      for (int s = 0; s < 2; ++s) {
        short8 a = *(const short8*)&afrag[mt*1024 + s*512 + lane*8];
        #pragma unroll
        for (int nt = 0; nt < 4; ++nt)
          acc5[mi][nt] = __builtin_amdgcn_mfma_f32_16x16x32_bf16(a, bw5[nt*2 + s], acc5[mi][nt], 0, 0, 0);
      }
    }
  }
  __syncthreads();   // all afrag reads done before fp32 reuse (regions overlap across waves)

  { // epilogue: out = y + b5g + conv5, fp32, coalesced via LDS transpose (own-wave rows)
    const float* b5g = wb + 29888;
    float b5f[4];
    #pragma unroll
    for (int nt = 0; nt < 4; ++nt) b5f[nt] = b5g[nt*16 + (lane & 15)];
    float* op = out + (size_t)b*64*HW + h*256;
    for (int chalf = 0; chalf < 2; ++chalf) {
      #pragma unroll
      for (int mi = 0; mi < 4; ++mi) {
        int pxb = (w*4 + mi)*16 + ((lane >> 4) << 2);
        #pragma unroll
        for (int nt2 = 0; nt2 < 2; ++nt2) {
          int nt = chalf*2 + nt2;
          int c = nt*16 + (lane & 15);
          #pragma unroll
          for (int r = 0; r < 4; ++r) {
            float v = acc5[mi][nt][r] + b5f[nt] + bf2f(yb[(pxb + r)*72 + c]);
            afragF[(pxb + r)*33 + (c - chalf*32)] = v;
          }
        }
      }
      // own-wave rows: thread tid reads row tid (written by its own wave) — no barrier needed
      #pragma unroll 4
      for (int cc = 0; cc < 32; ++cc)
        op[(size_t)(chalf*32 + cc) * HW + tid] = afragF[tid*33 + cc];
    }
  }
}

extern "C" void kernel_launch(void* const* d_in, const int* in_sizes, int n_in,
                              void* d_out, int out_size, void* d_ws, size_t ws_size,
                              hipStream_t stream) {
  const float* inp   = (const float*)d_in[0];
  const float* probs = (const float*)d_in[1];
  const float* ln1w  = (const float*)d_in[2];
  const float* ln1b  = (const float*)d_in[3];
  const float* ln2w  = (const float*)d_in[4];
  const float* ln2b  = (const float*)d_in[5];
  const float* w1    = (const float*)d_in[6];
  const float* b1    = (const float*)d_in[7];
  const float* la1   = (const float*)d_in[8];
  const float* lb1   = (const float*)d_in[9];
  const float* w2    = (const float*)d_in[10];
  const float* b2    = (const float*)d_in[11];
  const float* la2   = (const float*)d_in[12];
  const float* lb2   = (const float*)d_in[13];
  const float* wsca  = (const float*)d_in[14];
  const float* bsca  = (const float*)d_in[15];
  const float* lasca = (const float*)d_in[16];
  const float* lbsca = (const float*)d_in[17];
  const float* w3    = (const float*)d_in[18];
  const float* b3    = (const float*)d_in[19];
  const float* la3   = (const float*)d_in[20];
  const float* lb3   = (const float*)d_in[21];
  const float* w4    = (const float*)d_in[22];
  const float* b4    = (const float*)d_in[23];
  const float* la4   = (const float*)d_in[24];
  const float* lb4   = (const float*)d_in[25];
  const float* w5    = (const float*)d_in[26];
  const float* b5    = (const float*)d_in[27];
  const float* la5   = (const float*)d_in[28];
  const float* lb5   = (const float*)d_in[29];
  const float* beta  = (const float*)d_in[30];
  const float* gamma = (const float*)d_in[31];

  char* wsb = (char*)d_ws;
  float* weff   = (float*)(wsb + WEFF_OFF);
  U16*   fragw  = (U16*)(wsb + FRAG_OFF);
  float* pooled = (float*)(wsb + POOL_OFF);
  float* scap   = (float*)(wsb + SCA_OFF);
  U16*   t1     = (U16*)(wsb + T1_OFF);
  U16*   zws    = (U16*)(wsb + Z_OFF);
  float* outp   = (float*)d_out;

  k_weights<<<dim3(4), dim3(256), 0, stream>>>(probs,
      w1, la1, lb1, w2, la2, lb2, wsca, lasca, lbsca,
      w3, la3, lb3, w4, la4, lb4, w5, la5, lb5,
      b3, b5, beta, gamma, weff, fragw);
  k_conv1<<<dim3(1024), dim3(256), 0, stream>>>(inp, ln1w, ln1b, b1, fragw, t1);
  k_dwgate<<<dim3(2048), dim3(256), 0, stream>>>(t1, weff, b2, zws);
  k_pool<<<dim3(256), dim3(256), 0, stream>>>(zws, pooled);
  k_sca<<<dim3(4), dim3(64), 0, stream>>>(bsca, weff, pooled, scap);
  k_stage2<<<dim3(1024), dim3(256), 0, stream>>>(inp, zws, scap, ln2w, ln2b, b4, weff, fragw, outp);
}

// Round 4
// 292.666 us; speedup vs baseline: 2.4416x; 1.1111x over previous
//
#include <hip/hip_runtime.h>
#include <hip/hip_bf16.h>

#define HW 65536
#define WST 29952   // per-sample fp32 effective-weight stride (floats)

typedef unsigned short U16;
typedef __attribute__((ext_vector_type(8))) short short8;
typedef __attribute__((ext_vector_type(4))) unsigned short us4;
typedef __attribute__((ext_vector_type(4))) float float4v;

// ws byte offsets
#define WEFF_OFF 0
#define FRAG_OFF 524288        // U16[4][24576]: w1f@0, w3f@8192, w4f@12288, w5f@20480
#define POOL_OFF 786432        // float[256]
#define SCA_OFF  787456        // float[256]
#define T1_OFF   1048576       // U16[4][128][HW]
#define Z_OFF    68157440      // U16[4][64][HW]

__device__ inline U16 f2bf(float f) {
  union { float f; unsigned u; } v; v.f = f;
  unsigned r = v.u + 0x7FFF + ((v.u >> 16) & 1);   // RNE
  return (U16)(r >> 16);
}
__device__ inline float bf2f(U16 h) {
  union { unsigned u; float f; } v; v.u = ((unsigned)h) << 16;
  return v.f;
}
__device__ inline float asfhi(unsigned u) {   // high bf16 of dword
  union { unsigned u; float f; } v; v.u = u & 0xffff0000u; return v.f;
}
__device__ inline float asflo(unsigned u) {   // low bf16 of dword
  union { unsigned u; float f; } v; v.u = u << 16; return v.f;
}

// ---------------- kernel 1: per-sample effective weights + bf16 MFMA B-fragments ----
// 24 blocks = 4 samples x 6 sections; la/lb expert slices staged in LDS so per-element
// compute has no dependent global-load chains (was 52 us latency-bound on 4 blocks).
__global__ __launch_bounds__(256) void k_weights(const float* __restrict__ probs,
    const float* __restrict__ w1, const float* __restrict__ la1, const float* __restrict__ lb1,
    const float* __restrict__ w2, const float* __restrict__ la2, const float* __restrict__ lb2,
    const float* __restrict__ wsca, const float* __restrict__ lasca, const float* __restrict__ lbsca,
    const float* __restrict__ w3, const float* __restrict__ la3, const float* __restrict__ lb3,
    const float* __restrict__ w4, const float* __restrict__ la4, const float* __restrict__ lb4,
    const float* __restrict__ w5, const float* __restrict__ la5, const float* __restrict__ lb5,
    const float* __restrict__ b3, const float* __restrict__ b5,
    const float* __restrict__ beta, const float* __restrict__ gamma,
    float* __restrict__ weff, U16* __restrict__ fragw)
{
  __shared__ float sb[4992];
  int blk = blockIdx.x;
  int b = blk / 6, sec = blk - b * 6;
  int tid = threadIdx.x;
  float p0 = probs[b*3+0], p1 = probs[b*3+1], p2 = probs[b*3+2];
  int e = 0; float g = p0;
  if (p1 > g) { g = p1; e = 1; }
  if (p2 > g) { g = p2; e = 2; }
  float s = 2.0f * g;               // SCALING * gate
  float* wfp = weff + b * WST;
  U16* fws = fragw + b * 24576;

  if (sec == 1) {
    // ---- w2e (depthwise 3x3, 1152) + folded biases ----
    const float* lbs = lb2 + e * 4608;
    const float* las = la2 + e * 36;
    for (int i = tid; i < 4608; i += 256) sb[i] = lbs[i];
    if (tid < 36) sb[4608 + tid] = las[tid];
    if (tid < 64) {
      sb[4644 + tid] = b3[tid];  sb[4708 + tid] = b5[tid];
      sb[4772 + tid] = beta[tid]; sb[4836 + tid] = gamma[tid];
    }
    __syncthreads();
    for (int idx = tid; idx < 1152; idx += 256) {
      int row = idx / 3, dx = idx - row * 3;
      float acc = w2[idx];
      #pragma unroll
      for (int r = 0; r < 12; ++r)
        acc += s * sb[row*12 + r] * sb[4608 + r*3 + dx];
      wfp[8192 + idx] = acc;
    }
    if (tid < 64) {
      wfp[29824 + tid] = sb[4644 + tid] * sb[4772 + tid];   // b3 * beta
      wfp[29888 + tid] = sb[4708 + tid] * sb[4836 + tid];   // b5 * gamma
    }
    return;
  }
  if (sec == 2) {
    // ---- wscat [c][k] @9344 (4096) ----
    const float* lbs = lbsca + e * 256;
    const float* las = lasca + e * 256;
    if (tid < 256) { sb[tid] = lbs[tid]; sb[256 + tid] = las[tid]; }
    __syncthreads();
    #pragma unroll 4
    for (int idx = tid; idx < 4096; idx += 256) {
      int c = idx >> 6, k = idx & 63;
      float acc = wsca[k*64 + c];
      #pragma unroll
      for (int r = 0; r < 4; ++r)
        acc += s * sb[k*4 + r] * sb[256 + r*64 + c];
      wfp[9344 + idx] = acc;
    }
    return;
  }

  // ---- fragment sections: value = (w[n*64+k] + s*lb[n][:]@la[:][k]) * scale[n] ----
  const float *w, *la, *lb, *scl = nullptr;
  int fo, cnt;
  if (sec == 0)      { w = w1; lb = lb1 + e*512; la = la1 + e*256; fo = 0;     cnt = 8192; }
  else if (sec == 3) { w = w3; lb = lb3 + e*256; la = la3 + e*256; fo = 8192;  cnt = 4096; scl = beta; }
  else if (sec == 4) { w = w4; lb = lb4 + e*512; la = la4 + e*256; fo = 12288; cnt = 8192; }
  else               { w = w5; lb = lb5 + e*256; la = la5 + e*256; fo = 20480; cnt = 4096; scl = gamma; }
  int nlb = (cnt == 8192) ? 512 : 256;
  for (int i = tid; i < nlb; i += 256) sb[i] = lb[i];
  if (tid < 256) sb[512 + tid] = la[tid];
  if (scl && tid < 64) sb[768 + tid] = scl[tid];
  __syncthreads();
  #pragma unroll 4
  for (int idx = tid; idx < cnt; idx += 256) {
    int j = idx & 7, l = (idx >> 3) & 63, s2 = (idx >> 9) & 1, nt = idx >> 10;
    int n = nt*16 + (l & 15), k = s2*32 + ((l >> 4) << 3) + j;
    float acc = w[n*64 + k];
    #pragma unroll
    for (int r = 0; r < 4; ++r)
      acc += s * sb[n*4 + r] * sb[512 + r*64 + k];
    if (scl) acc *= sb[768 + n];
    fws[fo + idx] = f2bf(acc);
  }
}

// ---------------- kernel 2: LN1 + conv1 (1x1, 64->128) via MFMA; t1 -> ws bf16 NCHW ----
// block = (b, h): one image row, M=256 px, N=128, K=64.
__global__ __launch_bounds__(256, 2) void k_conv1(
    const float* __restrict__ inp, const float* __restrict__ ln1w, const float* __restrict__ ln1b,
    const float* __restrict__ b1, const U16* __restrict__ fragw, U16* __restrict__ t1)
{
  __shared__ __align__(16) U16 sm[16640];  // afrag 16384 (16 mt x 2 s x 64 l x 8), t1buf 64*260
  int blk = blockIdx.x;
  int b = blk >> 8, h = blk & 255;
  int tid = threadIdx.x, lane = tid & 63, w = tid >> 6;

  { // phase 1: LN1 per pixel, write A-fragments
    const float* src = inp + (size_t)b*64*HW + h*256 + tid;
    float x[64];
    #pragma unroll
    for (int c = 0; c < 64; ++c) x[c] = src[(size_t)c * HW];
    float s0=0,s1=0,q0=0,q1=0;
    #pragma unroll
    for (int c = 0; c < 64; c += 2) {
      s0 += x[c];   q0 += x[c]*x[c];
      s1 += x[c+1]; q1 += x[c+1]*x[c+1];
    }
    float mu  = (s0+s1) * (1.f/64.f);
    float inv = rsqrtf((q0+q1) * (1.f/64.f) - mu*mu + 1e-6f);
    #pragma unroll
    for (int c = 0; c < 64; ++c) x[c] = (x[c] - mu) * inv * ln1w[c] + ln1b[c];
    int mt = tid >> 4, m = tid & 15;
    #pragma unroll
    for (int s = 0; s < 2; ++s)
      #pragma unroll
      for (int q = 0; q < 4; ++q) {
        short8 v;
        #pragma unroll
        for (int j = 0; j < 8; ++j) v[j] = (short)f2bf(x[s*32 + q*8 + j]);
        *(short8*)&sm[mt*1024 + s*512 + (q*16 + m)*8] = v;
      }
  }
  __syncthreads();

  // phase 2: MFMA. wave w owns mt = 4w..4w+3, all 8 nt.
  const U16* fw = fragw + b * 24576;    // w1f
  short8 bw[16];
  #pragma unroll
  for (int i = 0; i < 16; ++i) bw[i] = *(const short8*)&fw[(i*64 + lane)*8];
  float4v acc[4][8];
  #pragma unroll
  for (int mi = 0; mi < 4; ++mi)
    #pragma unroll
    for (int nt = 0; nt < 8; ++nt) acc[mi][nt] = (float4v)(0.f);
  #pragma unroll
  for (int mi = 0; mi < 4; ++mi) {
    int mt = w*4 + mi;
    #pragma unroll
    for (int s = 0; s < 2; ++s) {
      short8 a = *(const short8*)&sm[mt*1024 + s*512 + lane*8];
      #pragma unroll
      for (int nt = 0; nt < 8; ++nt)
        acc[mi][nt] = __builtin_amdgcn_mfma_f32_16x16x32_bf16(a, bw[nt*2 + s], acc[mi][nt], 0, 0, 0);
    }
  }
  float b1v[8];
  #pragma unroll
  for (int nt = 0; nt < 8; ++nt) b1v[nt] = b1[nt*16 + (lane & 15)];
  __syncthreads();   // all afrag reads done before t1buf overwrite

  // phase 3: epilogue via LDS transpose, two 64-channel halves
  for (int half = 0; half < 2; ++half) {
    if (half) __syncthreads();
    #pragma unroll
    for (int mi = 0; mi < 4; ++mi) {
      int px0 = (w*4 + mi)*16 + ((lane >> 4) << 2);
      #pragma unroll
      for (int nt2 = 0; nt2 < 4; ++nt2) {
        int nt = half*4 + nt2;
        int jr = nt2*16 + (lane & 15);
        us4 pk;
        #pragma unroll
        for (int r = 0; r < 4; ++r) pk[r] = f2bf(acc[mi][nt][r] + b1v[nt]);
        *(us4*)&sm[jr*260 + px0] = pk;
      }
    }
    __syncthreads();
    U16* dst = t1 + ((size_t)(b*128 + half*64)) * HW + h*256;
    #pragma unroll 4
    for (int it = 0; it < 32; ++it) {
      int idx = it*256 + tid;
      int jr = idx >> 7, pp2 = (idx & 127) * 2;
      *(unsigned*)&dst[(size_t)jr * HW + pp2] = *(unsigned*)&sm[jr*260 + pp2];
    }
  }
}

// ---------------- kernel 3: depthwise 3x3 + SimpleGate -> z (bf16 NCHW) ----------------
// block = (b, row-pair, kg): 16 gated channels per block, thread = 2 pixels.
// grid 2048 (8 blocks/CU) + explicit load-phase per channel for ILP.
__global__ __launch_bounds__(256) void k_dwgate(
    const U16* __restrict__ t1, const float* __restrict__ weff, const float* __restrict__ b2,
    U16* __restrict__ z)
{
  int blk = blockIdx.x;
  int kg = blk & 3;                   // channel group: 16 gated channels
  int hp = (blk >> 2) & 127;
  int b  = blk >> 9;
  int tid = threadIdx.x;
  int h = hp*2 + (tid >> 7);          // wave-uniform row
  int px0 = (tid & 127) * 2;
  const float* w2e = weff + b*WST + 8192;
  const U16* tbase = t1 + (size_t)b*128*HW + (size_t)h*256 + px0;
  U16* zb = z + (size_t)b*64*HW + (size_t)h*256 + px0;
  bool okm = px0 > 0, okp = px0 < 254;
  bool ok0 = h > 0, ok2 = h < 255;    // wave-uniform

  #pragma unroll 2
  for (int kk = 0; kk < 16; ++kk) {
    int k = kg*16 + kk;
    const U16* ta = tbase + (size_t)k * HW;
    const U16* tc = ta + (size_t)64 * HW;
    // ---- load phase: all 18 dwords issued before any compute ----
    unsigned La[9], Lc[9];
    #pragma unroll
    for (int dy = 0; dy < 3; ++dy) {
      bool okr = (dy == 0) ? ok0 : (dy == 2 ? ok2 : true);
      int ro = (dy - 1) * 256;
      La[dy*3+0] = (okr && okm) ? *(const unsigned*)(ta + ro - 2) : 0u;
      La[dy*3+1] =  okr         ? *(const unsigned*)(ta + ro)     : 0u;
      La[dy*3+2] = (okr && okp) ? *(const unsigned*)(ta + ro + 2) : 0u;
    }
    #pragma unroll
    for (int dy = 0; dy < 3; ++dy) {
      bool okr = (dy == 0) ? ok0 : (dy == 2 ? ok2 : true);
      int ro = (dy - 1) * 256;
      Lc[dy*3+0] = (okr && okm) ? *(const unsigned*)(tc + ro - 2) : 0u;
      Lc[dy*3+1] =  okr         ? *(const unsigned*)(tc + ro)     : 0u;
      Lc[dy*3+2] = (okr && okp) ? *(const unsigned*)(tc + ro + 2) : 0u;
    }
    // ---- compute phase ----
    const float* wa = w2e + k*9;            // wave-uniform -> s_load
    const float* wc = w2e + (k+64)*9;
    float a0 = b2[k], a1 = a0;
    float c0 = b2[k+64], c1 = c0;
    #pragma unroll
    for (int dy = 0; dy < 3; ++dy) {
      float xm1 = asfhi(La[dy*3+0]), x0 = asflo(La[dy*3+1]);
      float x1  = asfhi(La[dy*3+1]), x2 = asflo(La[dy*3+2]);
      a0 += wa[dy*3]*xm1 + wa[dy*3+1]*x0 + wa[dy*3+2]*x1;
      a1 += wa[dy*3]*x0  + wa[dy*3+1]*x1 + wa[dy*3+2]*x2;
      xm1 = asfhi(Lc[dy*3+0]); x0 = asflo(Lc[dy*3+1]);
      x1  = asfhi(Lc[dy*3+1]); x2 = asflo(Lc[dy*3+2]);
      c0 += wc[dy*3]*xm1 + wc[dy*3+1]*x0 + wc[dy*3+2]*x1;
      c1 += wc[dy*3]*x0  + wc[dy*3+1]*x1 + wc[dy*3+2]*x2;
    }
    unsigned pz = (unsigned)f2bf(a0*c0) | ((unsigned)f2bf(a1*c1) << 16);
    *(unsigned*)(zb + (size_t)k * HW) = pz;
  }
}

// ---------------- kernel 4: pool over H*W per (b,k) ----------------
__global__ void k_pool(const U16* __restrict__ z, float* __restrict__ pooled)
{
  __shared__ float red[256];
  int b = blockIdx.x >> 6, k = blockIdx.x & 63;
  int tid = threadIdx.x;
  const unsigned* zp = (const unsigned*)(z + ((size_t)(b*64 + k)) * HW);
  float s = 0.f;
  for (int it = 0; it < 128; ++it) {
    unsigned u = zp[it*256 + tid];
    s += asflo(u) + asfhi(u);
  }
  red[tid] = s;
  __syncthreads();
  for (int st = 128; st >= 1; st >>= 1) {
    if (tid < st) red[tid] += red[tid + st];
    __syncthreads();
  }
  if (tid == 0) pooled[b*64 + k] = red[0];
}

// ---------------- kernel 5: sca[b][k] ----------------
__global__ void k_sca(const float* __restrict__ bsca, const float* __restrict__ weff,
                      const float* __restrict__ pooled, float* __restrict__ sca)
{
  int b = blockIdx.x, k = threadIdx.x;   // 64 threads
  const float* wt = weff + b * WST + 9344;   // wscat [c][k]
  const float* pm = pooled + b * 64;
  float acc = bsca[k];
  for (int c = 0; c < 64; ++c) acc += wt[c * 64 + k] * (pm[c] * (1.f/65536.f));
  sca[b * 64 + k] = acc;
}

// ---------------- kernel 6: xsca -> conv3 -> +inp (beta folded) -> LN2 -> conv4 -> gate -> conv5 ----
// block = (b, h): one image row. MFMA for conv3/conv4/conv5; per-pixel ops via LDS round-trips.
__global__ __launch_bounds__(256, 2) void k_stage2(
    const float* __restrict__ inp, const U16* __restrict__ z, const float* __restrict__ sca,
    const float* __restrict__ ln2w, const float* __restrict__ ln2b, const float* __restrict__ b4,
    const float* __restrict__ weff, const U16* __restrict__ fragw, float* __restrict__ out)
{
  __shared__ __align__(16) U16 yb[256*72];      // y, bf16, stride 72
  __shared__ __align__(16) char afr[34816];     // afrag U16[16384] / afragF float[256*33]
  U16* afrag = (U16*)afr;
  float* afragF = (float*)afr;
  int blk = blockIdx.x;
  int b = blk >> 8, h = blk & 255;
  int tid = threadIdx.x, lane = tid & 63, w = tid >> 6;
  const float* wb = weff + b * WST;
  const U16* fw = fragw + b * 24576;

  float y0[64];
  { // phase A: xs = z*sca -> A-frags; y0 = inp row
    const U16* zp = z + (size_t)b*64*HW + h*256 + tid;
    const float* scb = sca + b*64;
    float xs[64];
    #pragma unroll
    for (int k = 0; k < 64; ++k) xs[k] = bf2f(zp[(size_t)k * HW]) * scb[k];
    int mt = tid >> 4, m = tid & 15;
    #pragma unroll
    for (int s = 0; s < 2; ++s)
      #pragma unroll
      for (int q = 0; q < 4; ++q) {
        short8 v;
        #pragma unroll
        for (int j = 0; j < 8; ++j) v[j] = (short)f2bf(xs[s*32 + q*8 + j]);
        *(short8*)&afrag[mt*1024 + s*512 + (q*16 + m)*8] = v;
      }
    const float* ip = inp + (size_t)b*64*HW + h*256 + tid;
    #pragma unroll
    for (int c = 0; c < 64; ++c) y0[c] = ip[(size_t)c * HW];
  }
  __syncthreads();

  { // conv3: [256x64] @ w3bt[64x64] -> yb (bf16, pre-residual)
    short8 bw3[8];
    #pragma unroll
    for (int i = 0; i < 8; ++i) bw3[i] = *(const short8*)&fw[8192 + (i*64 + lane)*8];
    float4v acc[4][4];
    #pragma unroll
    for (int mi = 0; mi < 4; ++mi)
      #pragma unroll
      for (int nt = 0; nt < 4; ++nt) acc[mi][nt] = (float4v)(0.f);
    #pragma unroll
    for (int mi = 0; mi < 4; ++mi) {
      int mt = w*4 + mi;
      #pragma unroll
      for (int s = 0; s < 2; ++s) {
        short8 a = *(const short8*)&afrag[mt*1024 + s*512 + lane*8];
        #pragma unroll
        for (int nt = 0; nt < 4; ++nt)
          acc[mi][nt] = __builtin_amdgcn_mfma_f32_16x16x32_bf16(a, bw3[nt*2 + s], acc[mi][nt], 0, 0, 0);
      }
    }
    #pragma unroll
    for (int mi = 0; mi < 4; ++mi) {
      int pxb = (w*4 + mi)*16 + ((lane >> 4) << 2);
      #pragma unroll
      for (int nt = 0; nt < 4; ++nt) {
        int c = nt*16 + (lane & 15);
        #pragma unroll
        for (int r = 0; r < 4; ++r)
          yb[(pxb + r)*72 + c] = f2bf(acc[mi][nt][r]);
      }
    }
  }
  __syncthreads();

  { // phase C (thread = pixel): residual + LN2 -> xln A-frags; write y back (bf16)
    const float* b3b = wb + 29824;
    float y[64];
    #pragma unroll
    for (int c8 = 0; c8 < 8; ++c8) {
      short8 v = *(const short8*)&yb[tid*72 + c8*8];
      #pragma unroll
      for (int j = 0; j < 8; ++j) y[c8*8 + j] = bf2f((U16)v[j]);
    }
    #pragma unroll
    for (int c = 0; c < 64; ++c) y[c] += y0[c] + b3b[c];
    float s0=0,s1=0,q0=0,q1=0;
    #pragma unroll
    for (int c = 0; c < 64; c += 2) {
      s0 += y[c];   q0 += y[c]*y[c];
      s1 += y[c+1]; q1 += y[c+1]*y[c+1];
    }
    float mu  = (s0+s1) * (1.f/64.f);
    float inv = rsqrtf((q0+q1) * (1.f/64.f) - mu*mu + 1e-6f);
    int mt = tid >> 4, m = tid & 15;
    #pragma unroll
    for (int s = 0; s < 2; ++s)
      #pragma unroll
      for (int q = 0; q < 4; ++q) {
        short8 v;
        #pragma unroll
        for (int j = 0; j < 8; ++j) {
          int c = s*32 + q*8 + j;
          v[j] = (short)f2bf((y[c] - mu) * inv * ln2w[c] + ln2b[c]);
        }
        *(short8*)&afrag[mt*1024 + s*512 + (q*16 + m)*8] = v;
      }
    #pragma unroll
    for (int c8 = 0; c8 < 8; ++c8) {
      short8 v;
      #pragma unroll
      for (int j = 0; j < 8; ++j) v[j] = (short)f2bf(y[c8*8 + j]);
      *(short8*)&yb[tid*72 + c8*8] = v;
    }
  }
  __syncthreads();

  float4v acc5[4][4];
  { // conv4 (64->128) + in-register SimpleGate -> g A-frags (own-wave region) -> conv5
    short8 bw4[16];
    #pragma unroll
    for (int i = 0; i < 16; ++i) bw4[i] = *(const short8*)&fw[12288 + (i*64 + lane)*8];
    float b4a[8];
    #pragma unroll
    for (int nt = 0; nt < 8; ++nt) b4a[nt] = b4[nt*16 + (lane & 15)];
    float4v acc[4][8];
    #pragma unroll
    for (int mi = 0; mi < 4; ++mi)
      #pragma unroll
      for (int nt = 0; nt < 8; ++nt) acc[mi][nt] = (float4v)(0.f);
    #pragma unroll
    for (int mi = 0; mi < 4; ++mi) {
      int mt = w*4 + mi;
      #pragma unroll
      for (int s = 0; s < 2; ++s) {
        short8 a = *(const short8*)&afrag[mt*1024 + s*512 + lane*8];
        #pragma unroll
        for (int nt = 0; nt < 8; ++nt)
          acc[mi][nt] = __builtin_amdgcn_mfma_f32_16x16x32_bf16(a, bw4[nt*2 + s], acc[mi][nt], 0, 0, 0);
      }
    }
    // gate: t4[px][k] * t4[px][k+64] — same lane, same reg across nt / nt+4
    #pragma unroll
    for (int mi = 0; mi < 4; ++mi) {
      int mt = w*4 + mi;
      int mloc = ((lane >> 4) << 2);
      #pragma unroll
      for (int nt = 0; nt < 4; ++nt) {
        int k = nt*16 + (lane & 15);
        int s_ = k >> 5, q = (k >> 3) & 3, j = k & 7;
        #pragma unroll
        for (int r = 0; r < 4; ++r) {
          float gv = (acc[mi][nt][r] + b4a[nt]) * (acc[mi][nt+4][r] + b4a[nt+4]);
          afrag[mt*1024 + s_*512 + (q*16 + mloc + r)*8 + j] = f2bf(gv);
        }
      }
    }
    // conv5 reads only own-wave region (RAW within wave: no barrier needed)
    short8 bw5[8];
    #pragma unroll
    for (int i = 0; i < 8; ++i) bw5[i] = *(const short8*)&fw[20480 + (i*64 + lane)*8];
    #pragma unroll
    for (int mi = 0; mi < 4; ++mi)
      #pragma unroll
      for (int nt = 0; nt < 4; ++nt) acc5[mi][nt] = (float4v)(0.f);
    #pragma unroll
    for (int mi = 0; mi < 4; ++mi) {
      int mt = w*4 + mi;
      #pragma unroll
      for (int s = 0; s < 2; ++s) {
        short8 a = *(const short8*)&afrag[mt*1024 + s*512 + lane*8];
        #pragma unroll
        for (int nt = 0; nt < 4; ++nt)
          acc5[mi][nt] = __builtin_amdgcn_mfma_f32_16x16x32_bf16(a, bw5[nt*2 + s], acc5[mi][nt], 0, 0, 0);
      }
    }
  }
  __syncthreads();   // all afrag reads done before fp32 reuse (regions overlap across waves)

  { // epilogue: out = y + b5g + conv5, fp32, coalesced via LDS transpose (own-wave rows)
    const float* b5g = wb + 29888;
    float b5f[4];
    #pragma unroll
    for (int nt = 0; nt < 4; ++nt) b5f[nt] = b5g[nt*16 + (lane & 15)];
    float* op = out + (size_t)b*64*HW + h*256;
    for (int chalf = 0; chalf < 2; ++chalf) {
      #pragma unroll
      for (int mi = 0; mi < 4; ++mi) {
        int pxb = (w*4 + mi)*16 + ((lane >> 4) << 2);
        #pragma unroll
        for (int nt2 = 0; nt2 < 2; ++nt2) {
          int nt = chalf*2 + nt2;
          int c = nt*16 + (lane & 15);
          #pragma unroll
          for (int r = 0; r < 4; ++r) {
            float v = acc5[mi][nt][r] + b5f[nt] + bf2f(yb[(pxb + r)*72 + c]);
            afragF[(pxb + r)*33 + (c - chalf*32)] = v;
          }
        }
      }
      // own-wave rows: thread tid reads row tid (written by its own wave) — no barrier needed
      #pragma unroll 4
      for (int cc = 0; cc < 32; ++cc)
        op[(size_t)(chalf*32 + cc) * HW + tid] = afragF[tid*33 + cc];
    }
  }
}

extern "C" void kernel_launch(void* const* d_in, const int* in_sizes, int n_in,
                              void* d_out, int out_size, void* d_ws, size_t ws_size,
                              hipStream_t stream) {
  const float* inp   = (const float*)d_in[0];
  const float* probs = (const float*)d_in[1];
  const float* ln1w  = (const float*)d_in[2];
  const float* ln1b  = (const float*)d_in[3];
  const float* ln2w  = (const float*)d_in[4];
  const float* ln2b  = (const float*)d_in[5];
  const float* w1    = (const float*)d_in[6];
  const float* b1    = (const float*)d_in[7];
  const float* la1   = (const float*)d_in[8];
  const float* lb1   = (const float*)d_in[9];
  const float* w2    = (const float*)d_in[10];
  const float* b2    = (const float*)d_in[11];
  const float* la2   = (const float*)d_in[12];
  const float* lb2   = (const float*)d_in[13];
  const float* wsca  = (const float*)d_in[14];
  const float* bsca  = (const float*)d_in[15];
  const float* lasca = (const float*)d_in[16];
  const float* lbsca = (const float*)d_in[17];
  const float* w3    = (const float*)d_in[18];
  const float* b3    = (const float*)d_in[19];
  const float* la3   = (const float*)d_in[20];
  const float* lb3   = (const float*)d_in[21];
  const float* w4    = (const float*)d_in[22];
  const float* b4    = (const float*)d_in[23];
  const float* la4   = (const float*)d_in[24];
  const float* lb4   = (const float*)d_in[25];
  const float* w5    = (const float*)d_in[26];
  const float* b5    = (const float*)d_in[27];
  const float* la5   = (const float*)d_in[28];
  const float* lb5   = (const float*)d_in[29];
  const float* beta  = (const float*)d_in[30];
  const float* gamma = (const float*)d_in[31];

  char* wsb = (char*)d_ws;
  float* weff   = (float*)(wsb + WEFF_OFF);
  U16*   fragw  = (U16*)(wsb + FRAG_OFF);
  float* pooled = (float*)(wsb + POOL_OFF);
  float* scap   = (float*)(wsb + SCA_OFF);
  U16*   t1     = (U16*)(wsb + T1_OFF);
  U16*   zws    = (U16*)(wsb + Z_OFF);
  float* outp   = (float*)d_out;

  k_weights<<<dim3(24), dim3(256), 0, stream>>>(probs,
      w1, la1, lb1, w2, la2, lb2, wsca, lasca, lbsca,
      w3, la3, lb3, w4, la4, lb4, w5, la5, lb5,
      b3, b5, beta, gamma, weff, fragw);
  k_conv1<<<dim3(1024), dim3(256), 0, stream>>>(inp, ln1w, ln1b, b1, fragw, t1);
  k_dwgate<<<dim3(2048), dim3(256), 0, stream>>>(t1, weff, b2, zws);
  k_pool<<<dim3(256), dim3(256), 0, stream>>>(zws, pooled);
  k_sca<<<dim3(4), dim3(64), 0, stream>>>(bsca, weff, pooled, scap);
  k_stage2<<<dim3(1024), dim3(256), 0, stream>>>(inp, zws, scap, ln2w, ln2b, b4, weff, fragw, outp);
}

// Round 5
// 289.671 us; speedup vs baseline: 2.4669x; 1.0103x over previous
//
#include <hip/hip_runtime.h>
#include <hip/hip_bf16.h>

#define HW 65536
#define WST 29952   // per-sample fp32 effective-weight stride (floats)

typedef unsigned short U16;
typedef __attribute__((ext_vector_type(8))) short short8;
typedef __attribute__((ext_vector_type(4))) unsigned short us4;
typedef __attribute__((ext_vector_type(4))) float float4v;

// ws byte offsets
#define WEFF_OFF 0
#define FRAG_OFF 524288        // U16[4][24576]: w1f@0, w3f@8192, w4f@12288, w5f@20480
#define POOL_OFF 786432        // float[256]
#define SCA_OFF  787456        // float[256]
#define Z_OFF    68157440      // U16[4][64][HW]

__device__ inline U16 f2bf(float f) {
  union { float f; unsigned u; } v; v.f = f;
  unsigned r = v.u + 0x7FFF + ((v.u >> 16) & 1);   // RNE
  return (U16)(r >> 16);
}
__device__ inline float bf2f(U16 h) {
  union { unsigned u; float f; } v; v.u = ((unsigned)h) << 16;
  return v.f;
}
__device__ inline float asfhi(unsigned u) {   // high bf16 of dword
  union { unsigned u; float f; } v; v.u = u & 0xffff0000u; return v.f;
}
__device__ inline float asflo(unsigned u) {   // low bf16 of dword
  union { unsigned u; float f; } v; v.u = u << 16; return v.f;
}

// ---------------- kernel 1: per-sample effective weights + bf16 MFMA B-fragments ----
// 24 blocks = 4 samples x 6 sections. Also computes S[n]=sum_c w1g (w1g = w1e*ln1w,
// bf16-rounded to match fragments) and Bn[n]=b1+sum_c w1e*ln1b for the LN-folded conv1.
__global__ __launch_bounds__(256) void k_weights(const float* __restrict__ probs,
    const float* __restrict__ w1, const float* __restrict__ la1, const float* __restrict__ lb1,
    const float* __restrict__ w2, const float* __restrict__ la2, const float* __restrict__ lb2,
    const float* __restrict__ wsca, const float* __restrict__ lasca, const float* __restrict__ lbsca,
    const float* __restrict__ w3, const float* __restrict__ la3, const float* __restrict__ lb3,
    const float* __restrict__ w4, const float* __restrict__ la4, const float* __restrict__ lb4,
    const float* __restrict__ w5, const float* __restrict__ la5, const float* __restrict__ lb5,
    const float* __restrict__ b3, const float* __restrict__ b5,
    const float* __restrict__ beta, const float* __restrict__ gamma,
    const float* __restrict__ ln1w, const float* __restrict__ ln1b, const float* __restrict__ b1,
    float* __restrict__ weff, U16* __restrict__ fragw)
{
  __shared__ float sb[5952];
  int blk = blockIdx.x;
  int b = blk / 6, sec = blk - b * 6;
  int tid = threadIdx.x;
  float p0 = probs[b*3+0], p1 = probs[b*3+1], p2 = probs[b*3+2];
  int e = 0; float g = p0;
  if (p1 > g) { g = p1; e = 1; }
  if (p2 > g) { g = p2; e = 2; }
  float s = 2.0f * g;               // SCALING * gate
  float* wfp = weff + b * WST;
  U16* fws = fragw + b * 24576;

  if (sec == 1) {
    // ---- w2e (depthwise 3x3, 1152) + folded biases + S/Bn for conv1 LN-fold ----
    const float* lbs = lb2 + e * 4608;
    const float* las = la2 + e * 36;
    for (int i = tid; i < 4608; i += 256) sb[i] = lbs[i];
    if (tid < 36) sb[4608 + tid] = las[tid];
    if (tid < 64) {
      sb[4644 + tid] = b3[tid];  sb[4708 + tid] = b5[tid];
      sb[4772 + tid] = beta[tid]; sb[4836 + tid] = gamma[tid];
      sb[5668 + tid] = ln1w[tid]; sb[5732 + tid] = ln1b[tid];
    }
    if (tid < 256) sb[4900 + tid] = la1[e*256 + tid];
    for (int i = tid; i < 512; i += 256) sb[5156 + i] = lb1[e*512 + i];
    if (tid < 128) sb[5796 + tid] = b1[tid];
    __syncthreads();
    for (int idx = tid; idx < 1152; idx += 256) {
      int row = idx / 3, dx = idx - row * 3;
      float acc = w2[idx];
      #pragma unroll
      for (int r = 0; r < 12; ++r)
        acc += s * sb[row*12 + r] * sb[4608 + r*3 + dx];
      wfp[8192 + idx] = acc;
    }
    if (tid < 64) {
      wfp[29824 + tid] = sb[4644 + tid] * sb[4772 + tid];   // b3 * beta
      wfp[29888 + tid] = sb[4708 + tid] * sb[4836 + tid];   // b5 * gamma
    }
    if (tid >= 128) {
      int n = tid - 128;
      float S = 0.f, Bn = sb[5796 + n];
      for (int c = 0; c < 64; ++c) {
        float wv = w1[n*64 + c];
        #pragma unroll
        for (int r = 0; r < 4; ++r) wv += s * sb[5156 + n*4 + r] * sb[4900 + r*64 + c];
        S  += bf2f(f2bf(wv * sb[5668 + c]));    // match fragment rounding
        Bn += wv * sb[5732 + c];
      }
      wfp[n] = S; wfp[128 + n] = Bn;
    }
    return;
  }
  if (sec == 2) {
    // ---- wscat [c][k] @9344 (4096) ----
    const float* lbs = lbsca + e * 256;
    const float* las = lasca + e * 256;
    if (tid < 256) { sb[tid] = lbs[tid]; sb[256 + tid] = las[tid]; }
    __syncthreads();
    #pragma unroll 4
    for (int idx = tid; idx < 4096; idx += 256) {
      int c = idx >> 6, k = idx & 63;
      float acc = wsca[k*64 + c];
      #pragma unroll
      for (int r = 0; r < 4; ++r)
        acc += s * sb[k*4 + r] * sb[256 + r*64 + c];
      wfp[9344 + idx] = acc;
    }
    return;
  }

  // ---- fragment sections: value = (w[n*64+k] + s*lb[n][:]@la[:][k]) * scale ----
  const float *w, *la, *lb, *scl = nullptr;
  bool sclk = false;
  int fo, cnt;
  if (sec == 0)      { w = w1; lb = lb1 + e*512; la = la1 + e*256; fo = 0;     cnt = 8192; scl = ln1w; sclk = true; }
  else if (sec == 3) { w = w3; lb = lb3 + e*256; la = la3 + e*256; fo = 8192;  cnt = 4096; scl = beta; }
  else if (sec == 4) { w = w4; lb = lb4 + e*512; la = la4 + e*256; fo = 12288; cnt = 8192; }
  else               { w = w5; lb = lb5 + e*256; la = la5 + e*256; fo = 20480; cnt = 4096; scl = gamma; }
  int nlb = (cnt == 8192) ? 512 : 256;
  for (int i = tid; i < nlb; i += 256) sb[i] = lb[i];
  if (tid < 256) sb[512 + tid] = la[tid];
  if (scl && tid < 64) sb[768 + tid] = scl[tid];
  __syncthreads();
  #pragma unroll 4
  for (int idx = tid; idx < cnt; idx += 256) {
    int j = idx & 7, l = (idx >> 3) & 63, s2 = (idx >> 9) & 1, nt = idx >> 10;
    int n = nt*16 + (l & 15), k = s2*32 + ((l >> 4) << 3) + j;
    float acc = w[n*64 + k];
    #pragma unroll
    for (int r = 0; r < 4; ++r)
      acc += s * sb[n*4 + r] * sb[512 + r*64 + k];
    if (scl) acc *= sb[768 + (sclk ? k : n)];
    fws[fo + idx] = f2bf(acc);
  }
}

// ---------------- kernel 2 (fused): LN1 + conv1 (MFMA) + dw3x3 + SimpleGate + pool ----
// block = (b, group, 8x32 tile). t1 never leaves LDS. Group g computes gated
// channels g*32..g*32+31 (t1 channels g*32+i and 64+g*32+i). 2048 blocks.
#define MTS 22   // m-tiles for 340 halo px
__global__ __launch_bounds__(256, 3) void k_stage1f(
    const float* __restrict__ inp, const float* __restrict__ b2,
    const float* __restrict__ weff, const U16* __restrict__ fragw,
    U16* __restrict__ z, float* __restrict__ pooled)
{
  __shared__ __align__(16) U16 smu[22528];   // union: afrag (22*1024) / t1s (64*348)
  __shared__ float2 muinv[344];
  __shared__ float poolbuf[4][16];
  int blk = blockIdx.x;
  int tile = blk & 255;
  int g = (blk >> 8) & 1;
  int b = blk >> 9;
  int h0 = (tile >> 3) * 8, w0 = (tile & 7) * 32;
  int tid = threadIdx.x, lane = tid & 63, w = tid >> 6;
  const float* wfp = weff + b * WST;
  const U16* fw = fragw + b * 24576;

  // ---- P1: raw inp -> mu/inv + bf16 A-frags (no normalize; LN folded in epilogue) ----
  for (int it = 0; it < 2; ++it) {
    int i = tid + it * 256;
    if (i >= 340) break;
    int hy = i / 34, hx = i - hy * 34;
    int h = h0 - 1 + hy, ww = w0 - 1 + hx;
    int mt = i >> 4, m = i & 15;
    if (h >= 0 && h < 256 && ww >= 0 && ww < 256) {
      const float* src = inp + (size_t)b * 64 * HW + h * 256 + ww;
      float x[64];
      #pragma unroll
      for (int c = 0; c < 64; ++c) x[c] = src[(size_t)c * HW];
      float s0=0,s1=0,q0=0,q1=0;
      #pragma unroll
      for (int c = 0; c < 64; c += 2) {
        s0 += x[c];   q0 += x[c]*x[c];
        s1 += x[c+1]; q1 += x[c+1]*x[c+1];
      }
      float mu  = (s0+s1) * (1.f/64.f);
      float inv = rsqrtf(fmaxf((q0+q1)*(1.f/64.f) - mu*mu, 0.f) + 1e-6f);
      muinv[i] = float2{mu, inv};
      #pragma unroll
      for (int s = 0; s < 2; ++s)
        #pragma unroll
        for (int q = 0; q < 4; ++q) {
          short8 v;
          #pragma unroll
          for (int j = 0; j < 8; ++j) v[j] = (short)f2bf(x[s*32 + q*8 + j]);
          *(short8*)&smu[mt*1024 + s*512 + (q*16 + m)*8] = v;
        }
    } else {
      muinv[i] = float2{0.f, 0.f};   // inv==0 flags "outside image" -> t1 = 0
    }
  }

  // B-frags + S/Bn for this group's 4 n-tiles (done pre-barrier; independent of LDS)
  int n15 = lane & 15;
  short8 bw[8];
  float Sr[4], Br[4];
  #pragma unroll
  for (int ntl = 0; ntl < 4; ++ntl) {
    int ntg = (ntl < 2) ? (g*2 + ntl) : (4 + g*2 + (ntl - 2));
    #pragma unroll
    for (int s = 0; s < 2; ++s)
      bw[ntl*2 + s] = *(const short8*)&fw[((ntg*2 + s)*64 + lane)*8];
    int ng = ntg*16 + n15;
    Sr[ntl] = wfp[ng];
    Br[ntl] = wfp[128 + ng];
  }
  __syncthreads();

  // ---- P2: MFMA (raw-x conv1 with pre-scaled weights) ----
  int mt0 = w * 6;
  int nmt = MTS - mt0; if (nmt > 6) nmt = 6;   // 6,6,6,4
  float4v acc[6][4];
  #pragma unroll
  for (int mi = 0; mi < 6; ++mi)
    #pragma unroll
    for (int ntl = 0; ntl < 4; ++ntl) acc[mi][ntl] = (float4v)(0.f);
  #pragma unroll
  for (int mi = 0; mi < 6; ++mi) {
    if (mi < nmt) {
      int mt = mt0 + mi;
      #pragma unroll
      for (int s = 0; s < 2; ++s) {
        short8 a = *(const short8*)&smu[mt*1024 + s*512 + lane*8];
        #pragma unroll
        for (int ntl = 0; ntl < 4; ++ntl)
          acc[mi][ntl] = __builtin_amdgcn_mfma_f32_16x16x32_bf16(a, bw[ntl*2 + s], acc[mi][ntl], 0, 0, 0);
      }
    }
  }
  __syncthreads();   // afrag dead; smu becomes t1s[64][348]

  // ---- P3: epilogue t1 = inv*(A - mu*S) + Bn (0 outside image) -> t1s ----
  int q = lane >> 4;
  #pragma unroll
  for (int mi = 0; mi < 6; ++mi) {
    if (mi < nmt) {
      int px0 = (mt0 + mi)*16 + q*4;
      if (px0 < 340) {
        float2 m0 = muinv[px0], m1 = muinv[px0+1], m2 = muinv[px0+2], m3 = muinv[px0+3];
        #pragma unroll
        for (int ntl = 0; ntl < 4; ++ntl) {
          float S = Sr[ntl], B = Br[ntl];
          us4 pk;
          float v0 = m0.y*(acc[mi][ntl][0] - m0.x*S) + B;
          float v1 = m1.y*(acc[mi][ntl][1] - m1.x*S) + B;
          float v2 = m2.y*(acc[mi][ntl][2] - m2.x*S) + B;
          float v3 = m3.y*(acc[mi][ntl][3] - m3.x*S) + B;
          pk[0] = f2bf(m0.y > 0.f ? v0 : 0.f);
          pk[1] = f2bf(m1.y > 0.f ? v1 : 0.f);
          pk[2] = f2bf(m2.y > 0.f ? v2 : 0.f);
          pk[3] = f2bf(m3.y > 0.f ? v3 : 0.f);
          *(us4*)&smu[(ntl*16 + n15)*348 + px0] = pk;
        }
      }
    }
  }
  __syncthreads();

  // ---- P4: depthwise 3x3 + gate + z write + pool ----
  // thread = (channel half, 2-px pair). taps for even pair = 2 aligned dwords/row.
  {
    int half = tid >> 7;               // wave-uniform
    int pp = (tid & 127) * 2;
    int cy = pp >> 5, cx = pp & 31;
    const float* w2e = wfp + 8192;
    U16* zb = z + (size_t)b*64*HW + (size_t)(h0 + cy)*256 + (w0 + cx);
    #pragma unroll 2
    for (int i = 0; i < 16; ++i) {
      int kl = half*16 + i;
      int kg = g*32 + kl;
      unsigned ua[3][2], uc[3][2];
      #pragma unroll
      for (int dy = 0; dy < 3; ++dy) {
        int basea = kl*348 + (cy + dy)*34 + cx;
        int basec = (32 + kl)*348 + (cy + dy)*34 + cx;
        ua[dy][0] = *(unsigned*)&smu[basea]; ua[dy][1] = *(unsigned*)&smu[basea + 2];
        uc[dy][0] = *(unsigned*)&smu[basec]; uc[dy][1] = *(unsigned*)&smu[basec + 2];
      }
      const float* wa = w2e + kg*9;
      const float* wc = w2e + (kg + 64)*9;
      float a0 = b2[kg], a1 = a0;
      float c0 = b2[kg + 64], c1 = c0;
      #pragma unroll
      for (int dy = 0; dy < 3; ++dy) {
        float x0 = asflo(ua[dy][0]), x1 = asfhi(ua[dy][0]), x2 = asflo(ua[dy][1]), x3 = asfhi(ua[dy][1]);
        a0 += wa[dy*3]*x0 + wa[dy*3+1]*x1 + wa[dy*3+2]*x2;
        a1 += wa[dy*3]*x1 + wa[dy*3+1]*x2 + wa[dy*3+2]*x3;
        x0 = asflo(uc[dy][0]); x1 = asfhi(uc[dy][0]); x2 = asflo(uc[dy][1]); x3 = asfhi(uc[dy][1]);
        c0 += wc[dy*3]*x0 + wc[dy*3+1]*x1 + wc[dy*3+2]*x2;
        c1 += wc[dy*3]*x1 + wc[dy*3+1]*x2 + wc[dy*3+2]*x3;
      }
      float z0 = a0*c0, z1 = a1*c1;
      *(unsigned*)(zb + (size_t)kg * HW) = (unsigned)f2bf(z0) | ((unsigned)f2bf(z1) << 16);
      float ps = z0 + z1;
      #pragma unroll
      for (int off = 32; off >= 1; off >>= 1) ps += __shfl_down(ps, off, 64);
      if (lane == 0) poolbuf[w][i] = ps;
    }
  }
  __syncthreads();
  if (tid < 32) {
    float v = (tid < 16) ? (poolbuf[0][tid] + poolbuf[1][tid])
                         : (poolbuf[2][tid - 16] + poolbuf[3][tid - 16]);
    atomicAdd(&pooled[b*64 + g*32 + tid], v);
  }
}

// ---------------- kernel 3: sca[b][k] ----------------
__global__ void k_sca(const float* __restrict__ bsca, const float* __restrict__ weff,
                      const float* __restrict__ pooled, float* __restrict__ sca)
{
  int b = blockIdx.x, k = threadIdx.x;   // 64 threads
  const float* wt = weff + b * WST + 9344;   // wscat [c][k]
  const float* pm = pooled + b * 64;
  float acc = bsca[k];
  for (int c = 0; c < 64; ++c) acc += wt[c * 64 + k] * (pm[c] * (1.f/65536.f));
  sca[b * 64 + k] = acc;
}

// ---------------- kernel 4: xsca -> conv3 -> +inp (beta folded) -> LN2 -> conv4 -> gate -> conv5 ----
// block = (b, h): one image row. MFMA for conv3/conv4/conv5; per-pixel ops via LDS round-trips.
__global__ __launch_bounds__(256, 2) void k_stage2(
    const float* __restrict__ inp, const U16* __restrict__ z, const float* __restrict__ sca,
    const float* __restrict__ ln2w, const float* __restrict__ ln2b, const float* __restrict__ b4,
    const float* __restrict__ weff, const U16* __restrict__ fragw, float* __restrict__ out)
{
  __shared__ __align__(16) U16 yb[256*72];      // y, bf16, stride 72
  __shared__ __align__(16) char afr[34816];     // afrag U16[16384] / afragF float[256*33]
  U16* afrag = (U16*)afr;
  float* afragF = (float*)afr;
  int blk = blockIdx.x;
  int b = blk >> 8, h = blk & 255;
  int tid = threadIdx.x, lane = tid & 63, w = tid >> 6;
  const float* wb = weff + b * WST;
  const U16* fw = fragw + b * 24576;

  float y0[64];
  { // phase A: xs = z*sca -> A-frags; y0 = inp row
    const U16* zp = z + (size_t)b*64*HW + h*256 + tid;
    const float* scb = sca + b*64;
    float xs[64];
    #pragma unroll
    for (int k = 0; k < 64; ++k) xs[k] = bf2f(zp[(size_t)k * HW]) * scb[k];
    int mt = tid >> 4, m = tid & 15;
    #pragma unroll
    for (int s = 0; s < 2; ++s)
      #pragma unroll
      for (int q = 0; q < 4; ++q) {
        short8 v;
        #pragma unroll
        for (int j = 0; j < 8; ++j) v[j] = (short)f2bf(xs[s*32 + q*8 + j]);
        *(short8*)&afrag[mt*1024 + s*512 + (q*16 + m)*8] = v;
      }
    const float* ip = inp + (size_t)b*64*HW + h*256 + tid;
    #pragma unroll
    for (int c = 0; c < 64; ++c) y0[c] = ip[(size_t)c * HW];
  }
  __syncthreads();

  { // conv3: [256x64] @ w3bt[64x64] -> yb (bf16, pre-residual)
    short8 bw3[8];
    #pragma unroll
    for (int i = 0; i < 8; ++i) bw3[i] = *(const short8*)&fw[8192 + (i*64 + lane)*8];
    float4v acc[4][4];
    #pragma unroll
    for (int mi = 0; mi < 4; ++mi)
      #pragma unroll
      for (int nt = 0; nt < 4; ++nt) acc[mi][nt] = (float4v)(0.f);
    #pragma unroll
    for (int mi = 0; mi < 4; ++mi) {
      int mt = w*4 + mi;
      #pragma unroll
      for (int s = 0; s < 2; ++s) {
        short8 a = *(const short8*)&afrag[mt*1024 + s*512 + lane*8];
        #pragma unroll
        for (int nt = 0; nt < 4; ++nt)
          acc[mi][nt] = __builtin_amdgcn_mfma_f32_16x16x32_bf16(a, bw3[nt*2 + s], acc[mi][nt], 0, 0, 0);
      }
    }
    #pragma unroll
    for (int mi = 0; mi < 4; ++mi) {
      int pxb = (w*4 + mi)*16 + ((lane >> 4) << 2);
      #pragma unroll
      for (int nt = 0; nt < 4; ++nt) {
        int c = nt*16 + (lane & 15);
        #pragma unroll
        for (int r = 0; r < 4; ++r)
          yb[(pxb + r)*72 + c] = f2bf(acc[mi][nt][r]);
      }
    }
  }
  __syncthreads();

  { // phase C (thread = pixel): residual + LN2 -> xln A-frags; write y back (bf16)
    const float* b3b = wb + 29824;
    float y[64];
    #pragma unroll
    for (int c8 = 0; c8 < 8; ++c8) {
      short8 v = *(const short8*)&yb[tid*72 + c8*8];
      #pragma unroll
      for (int j = 0; j < 8; ++j) y[c8*8 + j] = bf2f((U16)v[j]);
    }
    #pragma unroll
    for (int c = 0; c < 64; ++c) y[c] += y0[c] + b3b[c];
    float s0=0,s1=0,q0=0,q1=0;
    #pragma unroll
    for (int c = 0; c < 64; c += 2) {
      s0 += y[c];   q0 += y[c]*y[c];
      s1 += y[c+1]; q1 += y[c+1]*y[c+1];
    }
    float mu  = (s0+s1) * (1.f/64.f);
    float inv = rsqrtf((q0+q1) * (1.f/64.f) - mu*mu + 1e-6f);
    int mt = tid >> 4, m = tid & 15;
    #pragma unroll
    for (int s = 0; s < 2; ++s)
      #pragma unroll
      for (int q = 0; q < 4; ++q) {
        short8 v;
        #pragma unroll
        for (int j = 0; j < 8; ++j) {
          int c = s*32 + q*8 + j;
          v[j] = (short)f2bf((y[c] - mu) * inv * ln2w[c] + ln2b[c]);
        }
        *(short8*)&afrag[mt*1024 + s*512 + (q*16 + m)*8] = v;
      }
    #pragma unroll
    for (int c8 = 0; c8 < 8; ++c8) {
      short8 v;
      #pragma unroll
      for (int j = 0; j < 8; ++j) v[j] = (short)f2bf(y[c8*8 + j]);
      *(short8*)&yb[tid*72 + c8*8] = v;
    }
  }
  __syncthreads();

  float4v acc5[4][4];
  { // conv4 (64->128) + in-register SimpleGate -> g A-frags (own-wave region) -> conv5
    short8 bw4[16];
    #pragma unroll
    for (int i = 0; i < 16; ++i) bw4[i] = *(const short8*)&fw[12288 + (i*64 + lane)*8];
    float b4a[8];
    #pragma unroll
    for (int nt = 0; nt < 8; ++nt) b4a[nt] = b4[nt*16 + (lane & 15)];
    float4v acc[4][8];
    #pragma unroll
    for (int mi = 0; mi < 4; ++mi)
      #pragma unroll
      for (int nt = 0; nt < 8; ++nt) acc[mi][nt] = (float4v)(0.f);
    #pragma unroll
    for (int mi = 0; mi < 4; ++mi) {
      int mt = w*4 + mi;
      #pragma unroll
      for (int s = 0; s < 2; ++s) {
        short8 a = *(const short8*)&afrag[mt*1024 + s*512 + lane*8];
        #pragma unroll
        for (int nt = 0; nt < 8; ++nt)
          acc[mi][nt] = __builtin_amdgcn_mfma_f32_16x16x32_bf16(a, bw4[nt*2 + s], acc[mi][nt], 0, 0, 0);
      }
    }
    // gate: t4[px][k] * t4[px][k+64] — same lane, same reg across nt / nt+4
    #pragma unroll
    for (int mi = 0; mi < 4; ++mi) {
      int mt = w*4 + mi;
      int mloc = ((lane >> 4) << 2);
      #pragma unroll
      for (int nt = 0; nt < 4; ++nt) {
        int k = nt*16 + (lane & 15);
        int s_ = k >> 5, q = (k >> 3) & 3, j = k & 7;
        #pragma unroll
        for (int r = 0; r < 4; ++r) {
          float gv = (acc[mi][nt][r] + b4a[nt]) * (acc[mi][nt+4][r] + b4a[nt+4]);
          afrag[mt*1024 + s_*512 + (q*16 + mloc + r)*8 + j] = f2bf(gv);
        }
      }
    }
    // conv5 reads only own-wave region (RAW within wave: no barrier needed)
    short8 bw5[8];
    #pragma unroll
    for (int i = 0; i < 8; ++i) bw5[i] = *(const short8*)&fw[20480 + (i*64 + lane)*8];
    #pragma unroll
    for (int mi = 0; mi < 4; ++mi)
      #pragma unroll
      for (int nt = 0; nt < 4; ++nt) acc5[mi][nt] = (float4v)(0.f);
    #pragma unroll
    for (int mi = 0; mi < 4; ++mi) {
      int mt = w*4 + mi;
      #pragma unroll
      for (int s = 0; s < 2; ++s) {
        short8 a = *(const short8*)&afrag[mt*1024 + s*512 + lane*8];
        #pragma unroll
        for (int nt = 0; nt < 4; ++nt)
          acc5[mi][nt] = __builtin_amdgcn_mfma_f32_16x16x32_bf16(a, bw5[nt*2 + s], acc5[mi][nt], 0, 0, 0);
      }
    }
  }
  __syncthreads();   // all afrag reads done before fp32 reuse (regions overlap across waves)

  { // epilogue: out = y + b5g + conv5, fp32, coalesced via LDS transpose (own-wave rows)
    const float* b5g = wb + 29888;
    float b5f[4];
    #pragma unroll
    for (int nt = 0; nt < 4; ++nt) b5f[nt] = b5g[nt*16 + (lane & 15)];
    float* op = out + (size_t)b*64*HW + h*256;
    for (int chalf = 0; chalf < 2; ++chalf) {
      #pragma unroll
      for (int mi = 0; mi < 4; ++mi) {
        int pxb = (w*4 + mi)*16 + ((lane >> 4) << 2);
        #pragma unroll
        for (int nt2 = 0; nt2 < 2; ++nt2) {
          int nt = chalf*2 + nt2;
          int c = nt*16 + (lane & 15);
          #pragma unroll
          for (int r = 0; r < 4; ++r) {
            float v = acc5[mi][nt][r] + b5f[nt] + bf2f(yb[(pxb + r)*72 + c]);
            afragF[(pxb + r)*33 + (c - chalf*32)] = v;
          }
        }
      }
      // own-wave rows: thread tid reads row tid (written by its own wave) — no barrier needed
      #pragma unroll 4
      for (int cc = 0; cc < 32; ++cc)
        op[(size_t)(chalf*32 + cc) * HW + tid] = afragF[tid*33 + cc];
    }
  }
}

extern "C" void kernel_launch(void* const* d_in, const int* in_sizes, int n_in,
                              void* d_out, int out_size, void* d_ws, size_t ws_size,
                              hipStream_t stream) {
  const float* inp   = (const float*)d_in[0];
  const float* probs = (const float*)d_in[1];
  const float* ln1w  = (const float*)d_in[2];
  const float* ln1b  = (const float*)d_in[3];
  const float* ln2w  = (const float*)d_in[4];
  const float* ln2b  = (const float*)d_in[5];
  const float* w1    = (const float*)d_in[6];
  const float* b1    = (const float*)d_in[7];
  const float* la1   = (const float*)d_in[8];
  const float* lb1   = (const float*)d_in[9];
  const float* w2    = (const float*)d_in[10];
  const float* b2    = (const float*)d_in[11];
  const float* la2   = (const float*)d_in[12];
  const float* lb2   = (const float*)d_in[13];
  const float* wsca  = (const float*)d_in[14];
  const float* bsca  = (const float*)d_in[15];
  const float* lasca = (const float*)d_in[16];
  const float* lbsca = (const float*)d_in[17];
  const float* w3    = (const float*)d_in[18];
  const float* b3    = (const float*)d_in[19];
  const float* la3   = (const float*)d_in[20];
  const float* lb3   = (const float*)d_in[21];
  const float* w4    = (const float*)d_in[22];
  const float* b4    = (const float*)d_in[23];
  const float* la4   = (const float*)d_in[24];
  const float* lb4   = (const float*)d_in[25];
  const float* w5    = (const float*)d_in[26];
  const float* b5    = (const float*)d_in[27];
  const float* la5   = (const float*)d_in[28];
  const float* lb5   = (const float*)d_in[29];
  const float* beta  = (const float*)d_in[30];
  const float* gamma = (const float*)d_in[31];

  char* wsb = (char*)d_ws;
  float* weff   = (float*)(wsb + WEFF_OFF);
  U16*   fragw  = (U16*)(wsb + FRAG_OFF);
  float* pooled = (float*)(wsb + POOL_OFF);
  float* scap   = (float*)(wsb + SCA_OFF);
  U16*   zws    = (U16*)(wsb + Z_OFF);
  float* outp   = (float*)d_out;

  hipMemsetAsync(pooled, 0, 256 * sizeof(float), stream);
  k_weights<<<dim3(24), dim3(256), 0, stream>>>(probs,
      w1, la1, lb1, w2, la2, lb2, wsca, lasca, lbsca,
      w3, la3, lb3, w4, la4, lb4, w5, la5, lb5,
      b3, b5, beta, gamma, ln1w, ln1b, b1, weff, fragw);
  k_stage1f<<<dim3(2048), dim3(256), 0, stream>>>(inp, b2, weff, fragw, zws, pooled);
  k_sca<<<dim3(4), dim3(64), 0, stream>>>(bsca, weff, pooled, scap);
  k_stage2<<<dim3(1024), dim3(256), 0, stream>>>(inp, zws, scap, ln2w, ln2b, b4, weff, fragw, outp);
}